// Round 13
// baseline (1497.458 us; speedup 1.0000x reference)
//
#include <hip/hip_runtime.h>

#define B_ 8
#define N_ 2048
#define KNN_ 20
#define DLS 2112   // skewed key-row stride (words): max j*66+63+1 = 2110 < 2112

typedef __attribute__((ext_vector_type(8))) short  s16x8;
typedef __attribute__((ext_vector_type(4))) short  s16x4;
typedef __attribute__((ext_vector_type(4))) float  f32x4;

__device__ __forceinline__ unsigned short bf16_rne(float f) {
    union { float f; unsigned u; } x; x.f = f;
    unsigned r = (x.u + 0x7fffu + ((x.u >> 16) & 1u)) >> 16;
    return (unsigned short)r;
}
__device__ __forceinline__ float bf16_f(unsigned short h) {
    union { unsigned u; float f; } x; x.u = ((unsigned)h) << 16; return x.f;
}
__device__ __forceinline__ f32x4 splat4(float v) { f32x4 r; r[0]=r[1]=r[2]=r[3]=v; return r; }
__device__ __forceinline__ unsigned key_flip(float f) {
    union { float f; unsigned u; } q; q.f = f;
    return (q.u & 0x80000000u) ? ~q.u : (q.u | 0x80000000u);
}

// ================= weight prep =================
__global__ void prep_edge_w(const float* __restrict__ W, unsigned short* nh, unsigned short* nl,
                            unsigned short* dh, unsigned short* dl, int O, int C) {
    int i = blockIdx.x * 256 + threadIdx.x;
    if (i >= O * C) return;
    int o = i / C, c = i % C;
    float wn = W[(size_t)o * 2 * C + c];
    float wd = W[(size_t)o * 2 * C + C + c] - wn;
    unsigned short h1 = bf16_rne(wn); nh[i] = h1; nl[i] = bf16_rne(wn - bf16_f(h1));
    unsigned short h2 = bf16_rne(wd); dh[i] = h2; dl[i] = bf16_rne(wd - bf16_f(h2));
}
__global__ void prep_w_hl(const float* __restrict__ W, int ld, int off,
                          unsigned short* wh, unsigned short* wl, int O, int C) {
    int i = blockIdx.x * 256 + threadIdx.x;
    if (i >= O * C) return;
    int o = i / C, c = i % C;
    float w = W[(size_t)o * ld + off + c];
    unsigned short h = bf16_rne(w); wh[i] = h; wl[i] = bf16_rne(w - bf16_f(h));
}
__global__ void prep_w1(const float* __restrict__ W, unsigned short* wh, int n) {
    int i = blockIdx.x * 256 + threadIdx.x;
    if (i < n) wh[i] = bf16_rne(W[i]);
}

// ================= xx precompute (row-major slice) =================
__global__ void xx_kernel(const float* __restrict__ xcat, int coff, int C, float* __restrict__ xx) {
    int i = blockIdx.x * 256 + threadIdx.x;      // global row id over B*N
    const float* r = xcat + (size_t)i * 512 + coff;
    float s = 0.f;
    for (int c = 0; c < C; c += 4) {
        f32x4 v = *(const f32x4*)(r + c);
        s += v[0] * v[0]; s += v[1] * v[1]; s += v[2] * v[2]; s += v[3] * v[3];
    }
    xx[i] = s;
}

// ================= transpose slice: xcat[b][n][coff+c] -> xT[b][c][n] =================
__global__ __launch_bounds__(256) void xpose_kernel(const float* __restrict__ xcat, int coff, int C,
                                                    float* __restrict__ xT) {
    __shared__ float t[64][65];
    int tid = threadIdx.x;
    int nct = C >> 6;
    int b = blockIdx.x / ((N_ / 64) * nct);
    int rem = blockIdx.x % ((N_ / 64) * nct);
    int nt = rem / nct, ct = rem % nct;
    int n0 = nt * 64, c0 = ct * 64;
    for (int k = 0; k < 16; ++k) {
        int idx = k * 256 + tid;
        int nl = idx >> 6, cl = idx & 63;
        t[nl][cl] = xcat[((size_t)b * N_ + n0 + nl) * 512 + coff + c0 + cl];
    }
    __syncthreads();
    for (int k = 0; k < 16; ++k) {
        int idx = k * 256 + tid;
        int cl = idx >> 6, nl = idx & 63;
        xT[((size_t)b * C + c0 + cl) * N_ + n0 + nl] = t[nl][cl];
    }
}

// ================= wave-local exact top-20 select + emit (r8-order-identical) =============
__device__ __forceinline__ void wave_select_emit(unsigned (&key)[32], int ln,
                                                 unsigned long long lower, int* __restrict__ orow) {
    unsigned T = 0u;
    bool early = false;
    for (int bit = 31; bit >= 0; --bit) {
        unsigned trial = T | (1u << bit);
        int cnt = 0;
        #pragma unroll
        for (int j = 0; j < 32; ++j)
            cnt += __popcll(__ballot(key[j] >= trial));
        if (cnt >= 20) {
            T = trial;
            if (cnt == 20) { early = true; break; }
        }
    }
    unsigned Tf = T;
    if (early) {
        unsigned mv = 0xFFFFFFFFu;
        #pragma unroll
        for (int j = 0; j < 32; ++j) {
            unsigned k = key[j];
            if (k >= T && k < mv) mv = k;
        }
        for (int off = 32; off; off >>= 1) {
            unsigned o = (unsigned)__shfl_xor((int)mv, off);
            if (o < mv) mv = o;
        }
        Tf = mv;
    }
    int base = 0;
    #pragma unroll
    for (int w = 0; w < 4; ++w) {
        #pragma unroll
        for (int j = 0; j < 8; ++j) {
            int jp = j * 4 + w;                       // r8 >T order: (w*8+j) ascending
            unsigned long long mG = __ballot(key[jp] > Tf);
            if (key[jp] > Tf) orow[base + __popcll(mG & lower)] = jp * 64 + ln;
            base += __popcll(mG);
        }
    }
    #pragma unroll
    for (int jp = 0; jp < 32; ++jp) {                 // ties: ascending index
        unsigned long long mE = __ballot(key[jp] == Tf);
        if (key[jp] == Tf) {
            int slot = base + __popcll(mE & lower);
            if (slot < 20) orow[slot] = jp * 64 + ln;
        }
        base += __popcll(mE);
    }
}

// ================= kNN layer 1 (C=3, 2-row x 4-pass key buffer, skewed) ==========
__global__ __launch_bounds__(256) void knn1_wl_kernel(const float* __restrict__ x,
                                                      int* __restrict__ idxout) {
    const int RT = 8;
    __shared__ unsigned DlU[2 * DLS];    // 16.9 KB, bank-skewed: 2 rows per pass
    __shared__ float Rc[3][RT];
    __shared__ float xxr_s[RT];

    int tid = threadIdx.x, ln = tid & 63, wv = tid >> 6;
    int b = blockIdx.x & 7, ng = blockIdx.x >> 3;
    int n0 = ng * RT;
    const float* xb = x + (size_t)b * 3 * N_;
    if (tid < 3 * RT) { int c = tid / RT, r = tid % RT; Rc[c][r] = xb[c * N_ + n0 + r]; }
    __syncthreads();
    if (tid < RT) {
        float s = 0.f;
        for (int c = 0; c < 3; ++c) { float v = Rc[c][tid]; s += v * v; }
        xxr_s[tid] = s;
    }
    __syncthreads();

    float d[RT][8], sqv[8];
    #pragma unroll
    for (int r = 0; r < RT; ++r)
        #pragma unroll
        for (int i = 0; i < 8; ++i) d[r][i] = 0.f;
    #pragma unroll
    for (int i = 0; i < 8; ++i) sqv[i] = 0.f;

    for (int c = 0; c < 3; ++c) {
        const float* col = xb + c * N_ + (tid << 3);
        f32x4 v0 = *(const f32x4*)col;
        f32x4 v1 = *(const f32x4*)(col + 4);
        #pragma unroll
        for (int i = 0; i < 4; ++i) {
            float v = v0[i];
            sqv[i] += v * v;
            #pragma unroll
            for (int r = 0; r < RT; ++r) d[r][i] += Rc[c][r] * v;
        }
        #pragma unroll
        for (int i = 0; i < 4; ++i) {
            float v = v1[i];
            sqv[4 + i] += v * v;
            #pragma unroll
            for (int r = 0; r < RT; ++r) d[r][4 + i] += Rc[c][r] * v;
        }
    }
    float xxr[RT];
    #pragma unroll
    for (int r = 0; r < RT; ++r) xxr[r] = xxr_s[r];

    int wbase = (tid << 3) + (tid >> 2);     // skew: w(m)=m+(m>>5), m=tid*8+i
    int rbase = ln + (ln >> 5);              // read: w(j*64+ln)=j*66+ln+(ln>>5)
    unsigned long long lower = (1ull << ln) - 1ull;
    #pragma unroll
    for (int q = 0; q < 4; ++q) {
        __syncthreads();
        #pragma unroll
        for (int rr = 0; rr < 2; ++rr) {
            int r = q * 2 + rr;
            unsigned* Dr = &DlU[rr * DLS + wbase];
            #pragma unroll
            for (int i = 0; i < 8; ++i)
                Dr[i] = key_flip(2.f * d[r][i] - xxr[r] - sqv[i]);
        }
        __syncthreads();
        if (wv < 2) {
            int row = q * 2 + wv;
            unsigned key[32];
            #pragma unroll
            for (int j = 0; j < 32; ++j) key[j] = DlU[wv * DLS + j * 66 + rbase];
            wave_select_emit(key, ln, lower, idxout + ((size_t)b * N_ + n0 + row) * KNN_);
        }
    }
}

// ================= kNN layers 2-4 (c-major xT, 2-row x 4-pass key buffer) ================
// Per-candidate key chain bit-identical to rounds 8-12.
template<int C>
__global__ __launch_bounds__(256) void knn_wl_kernel(const float* __restrict__ xT,
                                                     const float* __restrict__ xx,
                                                     int* __restrict__ idxout) {
    const int RT = 8;
    __shared__ unsigned DlU[2 * DLS];    // 16.9 KB, bank-skewed: 2 rows per pass
    __shared__ float Rc[C * RT];         // c-major queries: Rc[c*8+r]
    __shared__ float xxr_s[RT];

    int tid = threadIdx.x, ln = tid & 63, wv = tid >> 6;
    int b = blockIdx.x & 7, ng = blockIdx.x >> 3;      // XCD-affinity swizzle
    int n0 = ng * RT;
    const float* xb = xT + (size_t)b * C * N_;

    for (int t = tid; t < C * RT; t += 256) {
        int c = t >> 3, r = t & 7;
        Rc[t] = xb[(size_t)c * N_ + n0 + r];
    }
    if (tid < RT) xxr_s[tid] = xx[b * N_ + n0 + tid];
    __syncthreads();

    float d[RT][8];
    #pragma unroll
    for (int r = 0; r < RT; ++r)
        #pragma unroll
        for (int i = 0; i < 8; ++i) d[r][i] = 0.f;

    for (int c = 0; c < C; ++c) {
        f32x4 Q0 = *(const f32x4*)&Rc[c * 8];
        f32x4 Q1 = *(const f32x4*)&Rc[c * 8 + 4];
        const float* col = xb + (size_t)c * N_ + (tid << 3);
        f32x4 v0 = *(const f32x4*)col;
        f32x4 v1 = *(const f32x4*)(col + 4);
        #pragma unroll
        for (int i = 0; i < 4; ++i) {
            float v = v0[i];
            d[0][i] += Q0[0] * v; d[1][i] += Q0[1] * v; d[2][i] += Q0[2] * v; d[3][i] += Q0[3] * v;
            d[4][i] += Q1[0] * v; d[5][i] += Q1[1] * v; d[6][i] += Q1[2] * v; d[7][i] += Q1[3] * v;
        }
        #pragma unroll
        for (int i = 0; i < 4; ++i) {
            float v = v1[i];
            d[0][4+i] += Q0[0] * v; d[1][4+i] += Q0[1] * v; d[2][4+i] += Q0[2] * v; d[3][4+i] += Q0[3] * v;
            d[4][4+i] += Q1[0] * v; d[5][4+i] += Q1[1] * v; d[6][4+i] += Q1[2] * v; d[7][4+i] += Q1[3] * v;
        }
    }

    f32x4 xm0 = *(const f32x4*)(xx + b * N_ + (tid << 3));
    f32x4 xm1 = *(const f32x4*)(xx + b * N_ + (tid << 3) + 4);
    float xxr[RT];
    #pragma unroll
    for (int r = 0; r < RT; ++r) xxr[r] = xxr_s[r];

    int wbase = (tid << 3) + (tid >> 2);
    int rbase = ln + (ln >> 5);
    unsigned long long lower = (1ull << ln) - 1ull;
    #pragma unroll
    for (int q = 0; q < 4; ++q) {
        __syncthreads();
        #pragma unroll
        for (int rr = 0; rr < 2; ++rr) {
            int r = q * 2 + rr;
            unsigned* Dr = &DlU[rr * DLS + wbase];
            Dr[0] = key_flip(2.f * d[r][0] - xxr[r] - xm0[0]);
            Dr[1] = key_flip(2.f * d[r][1] - xxr[r] - xm0[1]);
            Dr[2] = key_flip(2.f * d[r][2] - xxr[r] - xm0[2]);
            Dr[3] = key_flip(2.f * d[r][3] - xxr[r] - xm0[3]);
            Dr[4] = key_flip(2.f * d[r][4] - xxr[r] - xm1[0]);
            Dr[5] = key_flip(2.f * d[r][5] - xxr[r] - xm1[1]);
            Dr[6] = key_flip(2.f * d[r][6] - xxr[r] - xm1[2]);
            Dr[7] = key_flip(2.f * d[r][7] - xxr[r] - xm1[3]);
        }
        __syncthreads();
        if (wv < 2) {
            int row = q * 2 + wv;
            unsigned key[32];
            #pragma unroll
            for (int j = 0; j < 32; ++j) key[j] = DlU[wv * DLS + j * 66 + rbase];
            wave_select_emit(key, ln, lower, idxout + ((size_t)b * N_ + n0 + row) * KNN_);
        }
    }
}

// ================= edge conv layer 1 (VALU, c-major, C=3) =================
template<int C, int O>
__global__ void edgeconv1_kernel(const float* __restrict__ src, int bstride,
                                 const float* __restrict__ W, const int* __restrict__ idx,
                                 float* __restrict__ maxh, float* __restrict__ part) {
    const int NT = 8, G = 256 / O, KT = KNN_ / G;
    __shared__ float nbr[KNN_][C];
    __shared__ float ctr[C];
    __shared__ int   jidx[KNN_];
    __shared__ float red[256];
    int tid = threadIdx.x;
    int b = blockIdx.x / (N_ / NT), n0 = (blockIdx.x % (N_ / NT)) * NT;
    int o = tid % O, sub = tid / O;
    const float* xb = src + (size_t)b * bstride;
    const float* Wl = W + (size_t)o * 2 * C;
    float ls = 0.f, lsq = 0.f;
    for (int nn = 0; nn < NT; ++nn) {
        int n = n0 + nn;
        if (tid < KNN_) jidx[tid] = idx[((size_t)b * N_ + n) * KNN_ + tid];
        __syncthreads();
        for (int t = tid; t < C; t += 256) ctr[t] = xb[t * N_ + n];
        for (int t = tid; t < KNN_ * C; t += 256) { int k = t / C, c = t % C; nbr[k][c] = xb[c * N_ + jidx[k]]; }
        __syncthreads();
        float hc = 0.f;
        for (int c = 0; c < C; ++c) hc += (Wl[C + c] - Wl[c]) * ctr[c];
        float h[KT];
        for (int i = 0; i < KT; ++i) h[i] = hc;
        for (int c = 0; c < C; ++c) { float w = Wl[c]; for (int i = 0; i < KT; ++i) h[i] += w * nbr[sub + i * G][c]; }
        float hmax = -1e30f;
        for (int i = 0; i < KT; ++i) { float v = h[i]; hmax = fmaxf(hmax, v); ls += v; lsq += v * v; }
        red[tid] = hmax; __syncthreads();
        if (sub == 0) {
            for (int s = 1; s < G; ++s) hmax = fmaxf(hmax, red[o + s * O]);
            maxh[((size_t)b * O + o) * N_ + n] = hmax;
        }
        __syncthreads();
    }
    red[tid] = ls; __syncthreads();
    if (sub == 0) for (int s = 1; s < G; ++s) ls += red[o + s * O];
    __syncthreads();
    red[tid] = lsq; __syncthreads();
    if (sub == 0) {
        for (int s = 1; s < G; ++s) lsq += red[o + s * O];
        part[((size_t)blockIdx.x * O + o) * 2 + 0] = ls;
        part[((size_t)blockIdx.x * O + o) * 2 + 1] = lsq;
    }
}

// ================= edge conv MFMA (layers 2-4), split-bf16 =================
template<int C, int O>
__global__ __launch_bounds__(256) void edge_mfma_kernel(
    const float* __restrict__ xcat, int coff,
    const unsigned short* __restrict__ Wnh, const unsigned short* __restrict__ Wnl,
    const unsigned short* __restrict__ Wdh, const unsigned short* __restrict__ Wdl,
    const int* __restrict__ idx, float* __restrict__ maxh, float* __restrict__ part) {
    const int LDA = C + 8;
    const int NKS = C / 32;
    const int OW  = O / 4;
    const int NOT = OW / 16;
    const int CPT = C / 16;
    __shared__ __align__(16) unsigned short sAh[16 * LDA];
    __shared__ __align__(16) unsigned short sAl[16 * LDA];
    __shared__ int js[16 * 20];
    int tid = threadIdx.x, ln = tid & 63, wv = tid >> 6;
    int lane15 = ln & 15, quad = ln >> 4;
    int b = blockIdx.x >> 7, n0 = (blockIdx.x & 127) * 16;
    const float* xb = xcat + (size_t)b * N_ * 512 + coff;

    for (int t = tid; t < 320; t += 256)
        js[t] = idx[((size_t)b * N_ + n0 + t / 20) * KNN_ + t % 20];

    f32x4 accMax[NOT], accSum[NOT], accSq[NOT], accHc[NOT];
    #pragma unroll
    for (int ot = 0; ot < NOT; ++ot) {
        accMax[ot] = splat4(-1e30f); accSum[ot] = splat4(0.f);
        accSq[ot] = splat4(0.f); accHc[ot] = splat4(0.f);
    }
    int srn = tid >> 4, sc0 = (tid & 15) * CPT;
    __syncthreads();

    for (int k = 0; k <= 20; ++k) {
        int j = (k < 20) ? js[srn * 20 + k] : (n0 + srn);
        const float* rp = xb + (size_t)j * 512 + sc0;
        unsigned short hi[CPT], lo[CPT];
        #pragma unroll
        for (int i4 = 0; i4 < CPT / 4; ++i4) {
            f32x4 v = *(const f32x4*)(rp + i4 * 4);
            #pragma unroll
            for (int e = 0; e < 4; ++e) {
                unsigned short h = bf16_rne(v[e]);
                hi[i4 * 4 + e] = h;
                lo[i4 * 4 + e] = bf16_rne(v[e] - bf16_f(h));
            }
        }
        __syncthreads();
        if (CPT == 8) {
            s16x8 ph, pl;
            #pragma unroll
            for (int e = 0; e < 8; ++e) { ph[e] = (short)hi[e]; pl[e] = (short)lo[e]; }
            *(s16x8*)&sAh[srn * LDA + sc0] = ph;
            *(s16x8*)&sAl[srn * LDA + sc0] = pl;
        } else {
            s16x4 ph, pl;
            #pragma unroll
            for (int e = 0; e < 4; ++e) { ph[e] = (short)hi[e]; pl[e] = (short)lo[e]; }
            *(s16x4*)&sAh[srn * LDA + sc0] = ph;
            *(s16x4*)&sAl[srn * LDA + sc0] = pl;
        }
        __syncthreads();
        s16x8 ah[NKS], al[NKS];
        #pragma unroll
        for (int ks = 0; ks < NKS; ++ks) {
            ah[ks] = *(const s16x8*)&sAh[lane15 * LDA + ks * 32 + quad * 8];
            al[ks] = *(const s16x8*)&sAl[lane15 * LDA + ks * 32 + quad * 8];
        }
        const unsigned short* Wh = (k < 20) ? Wnh : Wdh;
        const unsigned short* Wl = (k < 20) ? Wnl : Wdl;
        #pragma unroll
        for (int ot = 0; ot < NOT; ++ot) {
            int orow = wv * OW + ot * 16 + lane15;
            f32x4 dacc = splat4(0.f);
            #pragma unroll
            for (int ks = 0; ks < NKS; ++ks) {
                s16x8 bh = *(const s16x8*)&Wh[(size_t)orow * C + ks * 32 + quad * 8];
                s16x8 bl = *(const s16x8*)&Wl[(size_t)orow * C + ks * 32 + quad * 8];
                dacc = __builtin_amdgcn_mfma_f32_16x16x32_bf16(ah[ks], bh, dacc, 0, 0, 0);
                dacc = __builtin_amdgcn_mfma_f32_16x16x32_bf16(al[ks], bh, dacc, 0, 0, 0);
                dacc = __builtin_amdgcn_mfma_f32_16x16x32_bf16(ah[ks], bl, dacc, 0, 0, 0);
            }
            if (k < 20) {
                #pragma unroll
                for (int e = 0; e < 4; ++e) {
                    accMax[ot][e] = fmaxf(accMax[ot][e], dacc[e]);
                    accSum[ot][e] += dacc[e];
                    accSq[ot][e] += dacc[e] * dacc[e];
                }
            } else accHc[ot] = dacc;
        }
    }
    #pragma unroll
    for (int ot = 0; ot < NOT; ++ot) {
        int ocol = wv * OW + ot * 16 + lane15;
        float s = 0.f, q = 0.f;
        #pragma unroll
        for (int e = 0; e < 4; ++e) {
            float hc = accHc[ot][e];
            float mx = accMax[ot][e] + hc;
            float s20 = accSum[ot][e] + 20.f * hc;
            float q20 = accSq[ot][e] + 2.f * hc * accSum[ot][e] + 20.f * hc * hc;
            maxh[((size_t)b * N_ + n0 + quad * 4 + e) * O + ocol] = mx;
            s += s20; q += q20;
        }
        s += __shfl_xor(s, 16); s += __shfl_xor(s, 32);
        q += __shfl_xor(q, 16); q += __shfl_xor(q, 32);
        if (ln < 16) {
            int o = wv * OW + ot * 16 + ln;
            part[((size_t)blockIdx.x * O + o) * 2 + 0] = s;
            part[((size_t)blockIdx.x * O + o) * 2 + 1] = q;
        }
    }
}

// ================= conv1d MFMA (207/208/209), split-bf16 =================
template<int CIN, int O, bool HASB>
__global__ __launch_bounds__(256) void conv_mfma_kernel(
    const float* __restrict__ src, const unsigned short* __restrict__ Wh,
    const unsigned short* __restrict__ Wl, const float* __restrict__ bias,
    float* __restrict__ out, float* __restrict__ part) {
    const int LDA = 136;
    const int NOT = O / 16;
    __shared__ __align__(16) unsigned short sAh[64 * LDA];
    __shared__ __align__(16) unsigned short sAl[64 * LDA];
    int tid = threadIdx.x, ln = tid & 63, wv = tid >> 6;
    int lane15 = ln & 15, quad = ln >> 4;
    int b = blockIdx.x >> 5, n0 = (blockIdx.x & 31) * 64;
    const float* sb = src + ((size_t)b * N_ + n0) * CIN;

    f32x4 acc[NOT];
    #pragma unroll
    for (int ot = 0; ot < NOT; ++ot)
        acc[ot] = HASB ? splat4(bias[b * O + ot * 16 + lane15]) : splat4(0.f);

    int sr = tid >> 2, sc0 = (tid & 3) * 32;
    for (int cc = 0; cc < CIN / 128; ++cc) {
        __syncthreads();
        #pragma unroll
        for (int i4 = 0; i4 < 8; ++i4) {
            f32x4 v = *(const f32x4*)(sb + (size_t)sr * CIN + cc * 128 + sc0 + i4 * 4);
            s16x4 ph, pl;
            #pragma unroll
            for (int e = 0; e < 4; ++e) {
                unsigned short h = bf16_rne(v[e]);
                ph[e] = (short)h; pl[e] = (short)bf16_rne(v[e] - bf16_f(h));
            }
            *(s16x4*)&sAh[sr * LDA + sc0 + i4 * 4] = ph;
            *(s16x4*)&sAl[sr * LDA + sc0 + i4 * 4] = pl;
        }
        __syncthreads();
        s16x8 ah[4], al[4];
        #pragma unroll
        for (int ks = 0; ks < 4; ++ks) {
            ah[ks] = *(const s16x8*)&sAh[(wv * 16 + lane15) * LDA + ks * 32 + quad * 8];
            al[ks] = *(const s16x8*)&sAl[(wv * 16 + lane15) * LDA + ks * 32 + quad * 8];
        }
        #pragma unroll
        for (int ot = 0; ot < NOT; ++ot) {
            int orow = ot * 16 + lane15;
            const unsigned short* wrh = Wh + (size_t)orow * CIN + cc * 128;
            const unsigned short* wrl = Wl + (size_t)orow * CIN + cc * 128;
            #pragma unroll
            for (int ks = 0; ks < 4; ++ks) {
                s16x8 bh = *(const s16x8*)&wrh[ks * 32 + quad * 8];
                s16x8 bl = *(const s16x8*)&wrl[ks * 32 + quad * 8];
                acc[ot] = __builtin_amdgcn_mfma_f32_16x16x32_bf16(ah[ks], bh, acc[ot], 0, 0, 0);
                acc[ot] = __builtin_amdgcn_mfma_f32_16x16x32_bf16(al[ks], bh, acc[ot], 0, 0, 0);
                acc[ot] = __builtin_amdgcn_mfma_f32_16x16x32_bf16(ah[ks], bl, acc[ot], 0, 0, 0);
            }
        }
    }
    #pragma unroll
    for (int ot = 0; ot < NOT; ++ot) {
        int ocol = ot * 16 + lane15;
        float s = 0.f, q = 0.f;
        #pragma unroll
        for (int e = 0; e < 4; ++e) {
            float v = acc[ot][e];
            out[((size_t)b * N_ + n0 + wv * 16 + quad * 4 + e) * O + ocol] = v;
            s += v; q += v * v;
        }
        s += __shfl_xor(s, 16); s += __shfl_xor(s, 32);
        q += __shfl_xor(q, 16); q += __shfl_xor(q, 32);
        if (ln < 16) {
            part[(((size_t)blockIdx.x * 4 + wv) * O + ot * 16 + ln) * 2 + 0] = s;
            part[(((size_t)blockIdx.x * 4 + wv) * O + ot * 16 + ln) * 2 + 1] = q;
        }
    }
}

// ================= conv5 MFMA (stats + argmax tracking) =================
__global__ __launch_bounds__(256) void conv5_mfma_kernel(
    const float* __restrict__ xcat, const unsigned short* __restrict__ W5b,
    float* __restrict__ part, float* __restrict__ mpart, int* __restrict__ mipart) {
    const int LDA = 136;
    __shared__ __align__(16) unsigned short sA[16 * LDA];
    int tid = threadIdx.x, ln = tid & 63, wv = tid >> 6;
    int lane15 = ln & 15, quad = ln >> 4;
    int b = blockIdx.x >> 5, n00 = (blockIdx.x & 31) * 64;
    float sum[16], sq[16], mx[16]; int mi[16];
    #pragma unroll
    for (int ot = 0; ot < 16; ++ot) { sum[ot] = 0.f; sq[ot] = 0.f; mx[ot] = -1e30f; mi[ot] = 0; }
    int sr = tid >> 4, sc0 = (tid & 15) * 8;
    for (int mt = 0; mt < 4; ++mt) {
        int n0 = n00 + mt * 16;
        f32x4 acc[16];
        #pragma unroll
        for (int ot = 0; ot < 16; ++ot) acc[ot] = splat4(0.f);
        for (int cc = 0; cc < 4; ++cc) {
            __syncthreads();
            const float* rp = xcat + ((size_t)b * N_ + n0 + sr) * 512 + cc * 128 + sc0;
            f32x4 v0 = *(const f32x4*)(rp);
            f32x4 v1 = *(const f32x4*)(rp + 4);
            s16x8 p;
            #pragma unroll
            for (int e = 0; e < 4; ++e) { p[e] = (short)bf16_rne(v0[e]); p[4 + e] = (short)bf16_rne(v1[e]); }
            *(s16x8*)&sA[sr * LDA + sc0] = p;
            __syncthreads();
            s16x8 a[4];
            #pragma unroll
            for (int ks = 0; ks < 4; ++ks)
                a[ks] = *(const s16x8*)&sA[lane15 * LDA + ks * 32 + quad * 8];
            #pragma unroll
            for (int ot = 0; ot < 16; ++ot) {
                int orow = wv * 256 + ot * 16 + lane15;
                const unsigned short* wr = W5b + (size_t)orow * 512 + cc * 128;
                #pragma unroll
                for (int ks = 0; ks < 4; ++ks) {
                    s16x8 bh = *(const s16x8*)&wr[ks * 32 + quad * 8];
                    acc[ot] = __builtin_amdgcn_mfma_f32_16x16x32_bf16(a[ks], bh, acc[ot], 0, 0, 0);
                }
            }
        }
        #pragma unroll
        for (int ot = 0; ot < 16; ++ot) {
            #pragma unroll
            for (int e = 0; e < 4; ++e) {
                float v = acc[ot][e];
                sum[ot] += v; sq[ot] += v * v;
                if (v > mx[ot]) { mx[ot] = v; mi[ot] = n0 + quad * 4 + e; }
            }
        }
    }
    #pragma unroll
    for (int ot = 0; ot < 16; ++ot) {
        float s = sum[ot], q = sq[ot], m = mx[ot]; int im = mi[ot];
        s += __shfl_xor(s, 16); s += __shfl_xor(s, 32);
        q += __shfl_xor(q, 16); q += __shfl_xor(q, 32);
        { float m2 = __shfl_xor(m, 16); int i2 = __shfl_xor(im, 16); if (m2 > m) { m = m2; im = i2; } }
        { float m2 = __shfl_xor(m, 32); int i2 = __shfl_xor(im, 32); if (m2 > m) { m = m2; im = i2; } }
        if (ln < 16) {
            int o = wv * 256 + ot * 16 + ln;
            part[((size_t)blockIdx.x * 1024 + o) * 2 + 0] = s;
            part[((size_t)blockIdx.x * 1024 + o) * 2 + 1] = q;
            mpart[(size_t)blockIdx.x * 1024 + o] = m;
            mipart[(size_t)blockIdx.x * 1024 + o] = im;
        }
    }
}

// ================= BN stats =================
__global__ void bn_stats_kernel(const float* __restrict__ part, int nblk, int O, float count,
                                const float* __restrict__ g, const float* __restrict__ bb,
                                float* __restrict__ a, float* __restrict__ c) {
    __shared__ float s1[256], s2[256];
    int o = blockIdx.x; int tid = threadIdx.x;
    float ls = 0.f, lq = 0.f;
    for (int i = tid; i < nblk; i += 256) {
        ls += part[((size_t)i * O + o) * 2 + 0];
        lq += part[((size_t)i * O + o) * 2 + 1];
    }
    s1[tid] = ls; s2[tid] = lq; __syncthreads();
    for (int s = 128; s > 0; s >>= 1) {
        if (tid < s) { s1[tid] += s1[tid + s]; s2[tid] += s2[tid + s]; }
        __syncthreads();
    }
    if (tid == 0) {
        float mean = s1[0] / count;
        float var = fmaxf(s2[0] / count - mean * mean, 0.f);
        float scale = g[o] * rsqrtf(var + 1e-5f);
        a[o] = scale; c[o] = bb[o] - mean * scale;
    }
}

// ================= finalizes =================
__global__ void edge_fin1_kernel(const float* __restrict__ maxh, const float* __restrict__ a,
                                 const float* __restrict__ c, float* __restrict__ xcat) {
    __shared__ float t[64][33];
    int tid = threadIdx.x;
    int b = blockIdx.x >> 6, n0 = (blockIdx.x & 63) * 32;
    {
        int o = tid >> 2, g = tid & 3;
        const float* mp = maxh + ((size_t)b * 64 + o) * N_ + n0 + g * 8;
        for (int j = 0; j < 8; ++j) t[o][g * 8 + j] = mp[j];
    }
    __syncthreads();
    {
        int nl = tid >> 3, o0 = (tid & 7) * 8;
        float* op = xcat + ((size_t)b * N_ + n0 + nl) * 512 + o0;
        for (int j = 0; j < 8; ++j) {
            int o = o0 + j;
            float v = a[o] * t[o][nl] + c[o];
            op[j] = v >= 0.f ? v : 0.2f * v;
        }
    }
}

__global__ void edge_fin_rm_kernel(const float* __restrict__ maxh, const float* __restrict__ a,
                                   const float* __restrict__ c, int O, int coff,
                                   float* __restrict__ xcat) {
    int i = blockIdx.x * 256 + threadIdx.x;
    int o = i % O; size_t row = (size_t)(i / O);
    float v = a[o] * maxh[i] + c[o];
    xcat[row * 512 + coff + o] = v >= 0.f ? v : 0.2f * v;
}

// exact fp32 re-evaluation of h5 at the per-(b,o) argmax column
__global__ __launch_bounds__(256) void finalize5_exact_kernel(
    const float* __restrict__ mpart, const int* __restrict__ mipart,
    const float* __restrict__ xcat, const float* __restrict__ W5,
    const float* __restrict__ a, const float* __restrict__ c,
    float* __restrict__ glob) {
    int tid = threadIdx.x, ln = tid & 63, wv = tid >> 6;
    int p = blockIdx.x * 4 + wv;
    int b = p >> 10, o = p & 1023;
    float m = -1e30f; int mi = 0;
    if (ln < 32) {
        m = mpart[(size_t)(b * 32 + ln) * 1024 + o];
        mi = mipart[(size_t)(b * 32 + ln) * 1024 + o];
    }
    for (int off = 32; off; off >>= 1) {
        float m2 = __shfl_xor(m, off); int i2 = __shfl_xor(mi, off);
        if (m2 > m) { m = m2; mi = i2; }
    }
    const float* xr = xcat + ((size_t)b * N_ + mi) * 512 + ln * 8;
    const float* wr = W5 + (size_t)o * 512 + ln * 8;
    f32x4 x0 = *(const f32x4*)xr, x1 = *(const f32x4*)(xr + 4);
    f32x4 w0 = *(const f32x4*)wr, w1 = *(const f32x4*)(wr + 4);
    float s = x0[0] * w0[0] + x0[1] * w0[1] + x0[2] * w0[2] + x0[3] * w0[3]
            + x1[0] * w1[0] + x1[1] * w1[1] + x1[2] * w1[2] + x1[3] * w1[3];
    for (int off = 32; off; off >>= 1) s += __shfl_xor(s, off);
    if (ln == 0) {
        float v = a[o] * s + c[o];
        glob[b * 1088 + o] = v >= 0.f ? v : 0.2f * v;
    }
}

__global__ void lf_kernel(const float* __restrict__ l, const float* __restrict__ W206,
                          const float* __restrict__ g, const float* __restrict__ bb,
                          float* __restrict__ glob) {
    int tid = threadIdx.x;
    if (tid >= 64) return;
    float h[B_]; float s = 0.f, q = 0.f;
    for (int b = 0; b < B_; ++b) {
        float acc = 0.f;
        for (int c = 0; c < 16; ++c) acc += W206[tid * 16 + c] * l[b * 16 + c];
        h[b] = acc; s += acc; q += acc * acc;
    }
    float mean = s / B_;
    float var = fmaxf(q / B_ - mean * mean, 0.f);
    float scale = g[tid] * rsqrtf(var + 1e-5f);
    float off = bb[tid] - mean * scale;
    for (int b = 0; b < B_; ++b) {
        float v = scale * h[b] + off;
        glob[b * 1088 + 1024 + tid] = v >= 0.f ? v : 0.2f * v;
    }
}

__global__ void t207_kernel(const float* __restrict__ W207, const float* __restrict__ glob,
                            float* __restrict__ tbuf) {
    int b = blockIdx.x; int o = threadIdx.x;
    const float* Wr = W207 + (size_t)o * 1600;
    const float* gb = glob + b * 1088;
    float acc = 0.f;
    for (int c = 0; c < 1088; ++c) acc += Wr[c] * gb[c];
    tbuf[b * 256 + o] = acc;
}

__global__ void bn_act_rm_kernel(float* __restrict__ h, const float* __restrict__ a,
                                 const float* __restrict__ c, int O) {
    int i = blockIdx.x * 256 + threadIdx.x;
    int o = i % O;
    float v = a[o] * h[i] + c[o];
    h[i] = v >= 0.f ? v : 0.2f * v;
}

__global__ void final_rm_kernel(const float* __restrict__ src, const float* __restrict__ W,
                                float* __restrict__ out) {
    int i = blockIdx.x * 256 + threadIdx.x;
    if (i >= B_ * 50 * N_) return;
    int n = i % N_; int oc = (i / N_) % 50; int b = i / (N_ * 50);
    const float* xr = src + ((size_t)b * N_ + n) * 128;
    const float* Wr = W + oc * 128;
    float acc = 0.f;
    for (int c = 0; c < 128; c += 4) {
        f32x4 xv = *(const f32x4*)(xr + c);
        f32x4 wv = *(const f32x4*)(Wr + c);
        acc += xv[0] * wv[0] + xv[1] * wv[1] + xv[2] * wv[2] + xv[3] * wv[3];
    }
    out[i] = acc;
}

extern "C" void kernel_launch(void* const* d_in, const int* in_sizes, int n_in,
                              void* d_out, int out_size, void* d_ws, size_t ws_size,
                              hipStream_t stream) {
    const float* x     = (const float*)d_in[0];
    const float* l     = (const float*)d_in[1];
    const float* W1    = (const float*)d_in[2];
    const float* g1    = (const float*)d_in[3];
    const float* b1    = (const float*)d_in[4];
    const float* W2    = (const float*)d_in[5];
    const float* g2    = (const float*)d_in[6];
    const float* b2    = (const float*)d_in[7];
    const float* W3    = (const float*)d_in[8];
    const float* g3    = (const float*)d_in[9];
    const float* b3    = (const float*)d_in[10];
    const float* W4    = (const float*)d_in[11];
    const float* g4    = (const float*)d_in[12];
    const float* b4    = (const float*)d_in[13];
    const float* W5    = (const float*)d_in[14];
    const float* g5    = (const float*)d_in[15];
    const float* b5    = (const float*)d_in[16];
    const float* W206  = (const float*)d_in[17];
    const float* g206  = (const float*)d_in[18];
    const float* b206  = (const float*)d_in[19];
    const float* W207  = (const float*)d_in[20];
    const float* g207  = (const float*)d_in[21];
    const float* b207  = (const float*)d_in[22];
    const float* W208  = (const float*)d_in[23];
    const float* g208  = (const float*)d_in[24];
    const float* b208  = (const float*)d_in[25];
    const float* W209  = (const float*)d_in[26];
    const float* g209  = (const float*)d_in[27];
    const float* b209  = (const float*)d_in[28];
    const float* W2010 = (const float*)d_in[29];

    float* ws = (float*)d_ws;
    // ---- layout (float units), ~58.25 MB ----
    float* xcat = ws;                              // 8388608
    float* H1   = ws + 8388608;                    // 4194304 (maxh / h207 / h209 / xT)
    float* P    = ws + 12582912;                   // 1048576
    unsigned short* Wt = (unsigned short*)(ws + 13631488);  // 573440 fl
    int*   idxb = (int*)(ws + 14204928);           // 327680
    float* abuf = ws + 14532608;                   // 1024
    float* cbuf = ws + 14533632;                   // 1024
    float* glob = ws + 14534656;                   // 8704
    float* tbuf = ws + 14543360;                   // 2048
    float* xxb  = ws + 14545408;                   // 16384

    float* part5  = P;
    float* mpart5 = P + 524288;
    int*   mipart = (int*)(P + 786432);
    float* h207 = H1;
    float* h208 = xcat;
    float* h209 = H1;
    float* xT   = H1;   // overlay: dead between prev fin and edge_mfma's maxh write

    unsigned short* W2nh = Wt;            unsigned short* W2nl = Wt + 4096;
    unsigned short* W2dh = Wt + 8192;     unsigned short* W2dl = Wt + 12288;
    unsigned short* W3nh = Wt + 16384;    unsigned short* W3nl = Wt + 24576;
    unsigned short* W3dh = Wt + 32768;    unsigned short* W3dl = Wt + 40960;
    unsigned short* W4nh = Wt + 49152;    unsigned short* W4nl = Wt + 81920;
    unsigned short* W4dh = Wt + 114688;   unsigned short* W4dl = Wt + 147456;
    unsigned short* W5b  = Wt + 180224;
    unsigned short* W207h = Wt + 704512;  unsigned short* W207l = Wt + 835584;
    unsigned short* W208h = Wt + 966656;  unsigned short* W208l = Wt + 1032192;
    unsigned short* W209h = Wt + 1097728; unsigned short* W209l = Wt + 1130496;

    const float EC_CNT = (float)(B_ * N_ * KNN_);
    const float C1_CNT = (float)(B_ * N_);

    // ---- weight prep ----
    prep_edge_w<<<16, 256, 0, stream>>>(W2, W2nh, W2nl, W2dh, W2dl, 64, 64);
    prep_edge_w<<<32, 256, 0, stream>>>(W3, W3nh, W3nl, W3dh, W3dl, 128, 64);
    prep_edge_w<<<128, 256, 0, stream>>>(W4, W4nh, W4nl, W4dh, W4dl, 256, 128);
    prep_w1<<<2048, 256, 0, stream>>>(W5, W5b, 524288);
    prep_w_hl<<<512, 256, 0, stream>>>(W207, 1600, 1088, W207h, W207l, 256, 512);
    prep_w_hl<<<256, 256, 0, stream>>>(W208, 256, 0, W208h, W208l, 256, 256);
    prep_w_hl<<<128, 256, 0, stream>>>(W209, 256, 0, W209h, W209l, 128, 256);

    // ---- edge conv 1 (C=3) -> xcat cols [0,64) ----
    knn1_wl_kernel<<<2048, 256, 0, stream>>>(x, idxb);
    edgeconv1_kernel<3, 64><<<2048, 256, 0, stream>>>(x, 3 * N_, W1, idxb, H1, P);
    bn_stats_kernel<<<64, 256, 0, stream>>>(P, 2048, 64, EC_CNT, g1, b1, abuf, cbuf);
    edge_fin1_kernel<<<512, 256, 0, stream>>>(H1, abuf, cbuf, xcat);

    // ---- edge conv 2 (C=64 -> O=64) @ cols [64,128) ----
    xpose_kernel<<<256, 256, 0, stream>>>(xcat, 0, 64, xT);
    xx_kernel<<<64, 256, 0, stream>>>(xcat, 0, 64, xxb);
    knn_wl_kernel<64><<<2048, 256, 0, stream>>>(xT, xxb, idxb);
    edge_mfma_kernel<64, 64><<<1024, 256, 0, stream>>>(xcat, 0, W2nh, W2nl, W2dh, W2dl, idxb, H1, P);
    bn_stats_kernel<<<64, 256, 0, stream>>>(P, 1024, 64, EC_CNT, g2, b2, abuf, cbuf);
    edge_fin_rm_kernel<<<B_ * N_ * 64 / 256, 256, 0, stream>>>(H1, abuf, cbuf, 64, 64, xcat);

    // ---- edge conv 3 (C=64 -> O=128) @ cols [128,256) ----
    xpose_kernel<<<256, 256, 0, stream>>>(xcat, 64, 64, xT);
    xx_kernel<<<64, 256, 0, stream>>>(xcat, 64, 64, xxb);
    knn_wl_kernel<64><<<2048, 256, 0, stream>>>(xT, xxb, idxb);
    edge_mfma_kernel<64, 128><<<1024, 256, 0, stream>>>(xcat, 64, W3nh, W3nl, W3dh, W3dl, idxb, H1, P);
    bn_stats_kernel<<<128, 256, 0, stream>>>(P, 1024, 128, EC_CNT, g3, b3, abuf, cbuf);
    edge_fin_rm_kernel<<<B_ * N_ * 128 / 256, 256, 0, stream>>>(H1, abuf, cbuf, 128, 128, xcat);

    // ---- edge conv 4 (C=128 -> O=256) @ cols [256,512) ----
    xpose_kernel<<<512, 256, 0, stream>>>(xcat, 128, 128, xT);
    xx_kernel<<<64, 256, 0, stream>>>(xcat, 128, 128, xxb);
    knn_wl_kernel<128><<<2048, 256, 0, stream>>>(xT, xxb, idxb);
    edge_mfma_kernel<128, 256><<<1024, 256, 0, stream>>>(xcat, 128, W4nh, W4nl, W4dh, W4dl, idxb, H1, P);
    bn_stats_kernel<<<256, 256, 0, stream>>>(P, 1024, 256, EC_CNT, g4, b4, abuf, cbuf);
    edge_fin_rm_kernel<<<B_ * N_ * 256 / 256, 256, 0, stream>>>(H1, abuf, cbuf, 256, 256, xcat);

    // ---- conv5 (512 -> 1024) global max: bf16 stats + argmax, exact fp32 re-eval ----
    conv5_mfma_kernel<<<256, 256, 0, stream>>>(xcat, W5b, part5, mpart5, mipart);
    bn_stats_kernel<<<1024, 256, 0, stream>>>(part5, 256, 1024, C1_CNT, g5, b5, abuf, cbuf);
    lf_kernel<<<1, 64, 0, stream>>>(l, W206, g206, b206, glob);
    finalize5_exact_kernel<<<2048, 256, 0, stream>>>(mpart5, mipart, xcat, W5, abuf, cbuf, glob);
    t207_kernel<<<8, 256, 0, stream>>>(W207, glob, tbuf);

    // ---- conv 207 (512 -> 256) ----
    conv_mfma_kernel<512, 256, true><<<256, 256, 0, stream>>>(xcat, W207h, W207l, tbuf, h207, P);
    bn_stats_kernel<<<256, 256, 0, stream>>>(P, 1024, 256, C1_CNT, g207, b207, abuf, cbuf);
    bn_act_rm_kernel<<<B_ * N_ * 256 / 256, 256, 0, stream>>>(h207, abuf, cbuf, 256);

    // ---- conv 208 (256 -> 256) ----
    conv_mfma_kernel<256, 256, false><<<256, 256, 0, stream>>>(h207, W208h, W208l, nullptr, h208, P);
    bn_stats_kernel<<<256, 256, 0, stream>>>(P, 1024, 256, C1_CNT, g208, b208, abuf, cbuf);
    bn_act_rm_kernel<<<B_ * N_ * 256 / 256, 256, 0, stream>>>(h208, abuf, cbuf, 256);

    // ---- conv 209 (256 -> 128) ----
    conv_mfma_kernel<256, 128, false><<<256, 256, 0, stream>>>(h208, W209h, W209l, nullptr, h209, P);
    bn_stats_kernel<<<128, 256, 0, stream>>>(P, 1024, 128, C1_CNT, g209, b209, abuf, cbuf);
    bn_act_rm_kernel<<<B_ * N_ * 128 / 256, 256, 0, stream>>>(h209, abuf, cbuf, 128);

    // ---- final (128 -> 50), fp32 out ----
    final_rm_kernel<<<(B_ * 50 * N_ + 255) / 256, 256, 0, stream>>>(h209, W2010, (float*)d_out);
}

// Round 14
// 1241.271 us; speedup vs baseline: 1.2064x; 1.2064x over previous
//
#include <hip/hip_runtime.h>

#define B_ 8
#define N_ 2048
#define KNN_ 20
#define DLS 2112   // skewed key-row stride (words): max j*66+63+1 = 2110 < 2112

typedef __attribute__((ext_vector_type(8))) short  s16x8;
typedef __attribute__((ext_vector_type(4))) short  s16x4;
typedef __attribute__((ext_vector_type(4))) float  f32x4;

__device__ __forceinline__ unsigned short bf16_rne(float f) {
    union { float f; unsigned u; } x; x.f = f;
    unsigned r = (x.u + 0x7fffu + ((x.u >> 16) & 1u)) >> 16;
    return (unsigned short)r;
}
__device__ __forceinline__ float bf16_f(unsigned short h) {
    union { unsigned u; float f; } x; x.u = ((unsigned)h) << 16; return x.f;
}
__device__ __forceinline__ f32x4 splat4(float v) { f32x4 r; r[0]=r[1]=r[2]=r[3]=v; return r; }
__device__ __forceinline__ unsigned key_flip(float f) {
    union { float f; unsigned u; } q; q.f = f;
    return (q.u & 0x80000000u) ? ~q.u : (q.u | 0x80000000u);
}

// ================= weight prep =================
__global__ void prep_edge_w(const float* __restrict__ W, unsigned short* nh, unsigned short* nl,
                            unsigned short* dh, unsigned short* dl, int O, int C) {
    int i = blockIdx.x * 256 + threadIdx.x;
    if (i >= O * C) return;
    int o = i / C, c = i % C;
    float wn = W[(size_t)o * 2 * C + c];
    float wd = W[(size_t)o * 2 * C + C + c] - wn;
    unsigned short h1 = bf16_rne(wn); nh[i] = h1; nl[i] = bf16_rne(wn - bf16_f(h1));
    unsigned short h2 = bf16_rne(wd); dh[i] = h2; dl[i] = bf16_rne(wd - bf16_f(h2));
}
__global__ void prep_w_hl(const float* __restrict__ W, int ld, int off,
                          unsigned short* wh, unsigned short* wl, int O, int C) {
    int i = blockIdx.x * 256 + threadIdx.x;
    if (i >= O * C) return;
    int o = i / C, c = i % C;
    float w = W[(size_t)o * ld + off + c];
    unsigned short h = bf16_rne(w); wh[i] = h; wl[i] = bf16_rne(w - bf16_f(h));
}
__global__ void prep_w1(const float* __restrict__ W, unsigned short* wh, int n) {
    int i = blockIdx.x * 256 + threadIdx.x;
    if (i < n) wh[i] = bf16_rne(W[i]);
}

// ================= xx precompute (row-major slice) =================
__global__ void xx_kernel(const float* __restrict__ xcat, int coff, int C, float* __restrict__ xx) {
    int i = blockIdx.x * 256 + threadIdx.x;      // global row id over B*N
    const float* r = xcat + (size_t)i * 512 + coff;
    float s = 0.f;
    for (int c = 0; c < C; c += 4) {
        f32x4 v = *(const f32x4*)(r + c);
        s += v[0] * v[0]; s += v[1] * v[1]; s += v[2] * v[2]; s += v[3] * v[3];
    }
    xx[i] = s;
}

// ================= transpose slice: xcat[b][n][coff+c] -> xT[b][c][n] =================
__global__ __launch_bounds__(256) void xpose_kernel(const float* __restrict__ xcat, int coff, int C,
                                                    float* __restrict__ xT) {
    __shared__ float t[64][65];
    int tid = threadIdx.x;
    int nct = C >> 6;
    int b = blockIdx.x / ((N_ / 64) * nct);
    int rem = blockIdx.x % ((N_ / 64) * nct);
    int nt = rem / nct, ct = rem % nct;
    int n0 = nt * 64, c0 = ct * 64;
    for (int k = 0; k < 16; ++k) {
        int idx = k * 256 + tid;
        int nl = idx >> 6, cl = idx & 63;
        t[nl][cl] = xcat[((size_t)b * N_ + n0 + nl) * 512 + coff + c0 + cl];
    }
    __syncthreads();
    for (int k = 0; k < 16; ++k) {
        int idx = k * 256 + tid;
        int cl = idx >> 6, nl = idx & 63;
        xT[((size_t)b * C + c0 + cl) * N_ + n0 + nl] = t[nl][cl];
    }
}

// ================= wave-local exact top-20 select + emit (r8-order-identical) =============
__device__ __forceinline__ void wave_select_emit(unsigned (&key)[32], int ln,
                                                 unsigned long long lower, int* __restrict__ orow) {
    unsigned T = 0u;
    bool early = false;
    for (int bit = 31; bit >= 0; --bit) {
        unsigned trial = T | (1u << bit);
        int cnt = 0;
        #pragma unroll
        for (int j = 0; j < 32; ++j)
            cnt += __popcll(__ballot(key[j] >= trial));
        if (cnt >= 20) {
            T = trial;
            if (cnt == 20) { early = true; break; }
        }
    }
    unsigned Tf = T;
    if (early) {
        unsigned mv = 0xFFFFFFFFu;
        #pragma unroll
        for (int j = 0; j < 32; ++j) {
            unsigned k = key[j];
            if (k >= T && k < mv) mv = k;
        }
        for (int off = 32; off; off >>= 1) {
            unsigned o = (unsigned)__shfl_xor((int)mv, off);
            if (o < mv) mv = o;
        }
        Tf = mv;
    }
    int base = 0;
    #pragma unroll
    for (int w = 0; w < 4; ++w) {
        #pragma unroll
        for (int j = 0; j < 8; ++j) {
            int jp = j * 4 + w;                       // r8 >T order: (w*8+j) ascending
            unsigned long long mG = __ballot(key[jp] > Tf);
            if (key[jp] > Tf) orow[base + __popcll(mG & lower)] = jp * 64 + ln;
            base += __popcll(mG);
        }
    }
    #pragma unroll
    for (int jp = 0; jp < 32; ++jp) {                 // ties: ascending index
        unsigned long long mE = __ballot(key[jp] == Tf);
        if (key[jp] == Tf) {
            int slot = base + __popcll(mE & lower);
            if (slot < 20) orow[slot] = jp * 64 + ln;
        }
        base += __popcll(mE);
    }
}

// ================= kNN layer 1 (C=3, consecutive-candidate loads, skewed keys) ==========
__global__ __launch_bounds__(256) void knn1_wl_kernel(const float* __restrict__ x,
                                                      int* __restrict__ idxout) {
    const int RT = 8;
    __shared__ unsigned DlU[4 * DLS];    // 33.8 KB, bank-skewed
    __shared__ float Rc[3][RT];
    __shared__ float xxr_s[RT];

    int tid = threadIdx.x, ln = tid & 63, wv = tid >> 6;
    int b = blockIdx.x & 7, ng = blockIdx.x >> 3;
    int n0 = ng * RT;
    const float* xb = x + (size_t)b * 3 * N_;
    if (tid < 3 * RT) { int c = tid / RT, r = tid % RT; Rc[c][r] = xb[c * N_ + n0 + r]; }
    __syncthreads();
    if (tid < RT) {
        float s = 0.f;
        for (int c = 0; c < 3; ++c) { float v = Rc[c][tid]; s += v * v; }
        xxr_s[tid] = s;
    }
    __syncthreads();

    float d[RT][8], sqv[8];
    #pragma unroll
    for (int r = 0; r < RT; ++r)
        #pragma unroll
        for (int i = 0; i < 8; ++i) d[r][i] = 0.f;
    #pragma unroll
    for (int i = 0; i < 8; ++i) sqv[i] = 0.f;

    for (int c = 0; c < 3; ++c) {
        const float* col = xb + c * N_ + (tid << 3);
        f32x4 v0 = *(const f32x4*)col;
        f32x4 v1 = *(const f32x4*)(col + 4);
        #pragma unroll
        for (int i = 0; i < 4; ++i) {
            float v = v0[i];
            sqv[i] += v * v;
            #pragma unroll
            for (int r = 0; r < RT; ++r) d[r][i] += Rc[c][r] * v;
        }
        #pragma unroll
        for (int i = 0; i < 4; ++i) {
            float v = v1[i];
            sqv[4 + i] += v * v;
            #pragma unroll
            for (int r = 0; r < RT; ++r) d[r][4 + i] += Rc[c][r] * v;
        }
    }
    float xxr[RT];
    #pragma unroll
    for (int r = 0; r < RT; ++r) xxr[r] = xxr_s[r];

    int wbase = (tid << 3) + (tid >> 2);     // skew: w(m)=m+(m>>5), m=tid*8+i
    int rbase = ln + (ln >> 5);              // read: w(j*64+ln)=j*66+ln+(ln>>5)
    unsigned long long lower = (1ull << ln) - 1ull;
    #pragma unroll
    for (int half = 0; half < 2; ++half) {
        __syncthreads();
        #pragma unroll
        for (int rr = 0; rr < 4; ++rr) {
            int r = half * 4 + rr;
            unsigned* Dr = &DlU[rr * DLS + wbase];
            #pragma unroll
            for (int i = 0; i < 8; ++i)
                Dr[i] = key_flip(2.f * d[r][i] - xxr[r] - sqv[i]);
        }
        __syncthreads();
        int row = half * 4 + wv;
        unsigned key[32];
        #pragma unroll
        for (int j = 0; j < 32; ++j) key[j] = DlU[wv * DLS + j * 66 + rbase];
        wave_select_emit(key, ln, lower, idxout + ((size_t)b * N_ + n0 + row) * KNN_);
    }
}

// ================= kNN layers 2-4 (c-major xT, f32x4 loads, skewed keys) ================
// Per-candidate key chain bit-identical to rounds 8-12.
template<int C>
__global__ __launch_bounds__(256) void knn_wl_kernel(const float* __restrict__ xT,
                                                     const float* __restrict__ xx,
                                                     int* __restrict__ idxout) {
    const int RT = 8;
    __shared__ unsigned DlU[4 * DLS];    // 33.8 KB, bank-skewed
    __shared__ float Rc[C * RT];         // c-major queries: Rc[c*8+r]
    __shared__ float xxr_s[RT];

    int tid = threadIdx.x, ln = tid & 63, wv = tid >> 6;
    int b = blockIdx.x & 7, ng = blockIdx.x >> 3;      // XCD-affinity swizzle
    int n0 = ng * RT;
    const float* xb = xT + (size_t)b * C * N_;

    for (int t = tid; t < C * RT; t += 256) {
        int c = t >> 3, r = t & 7;
        Rc[t] = xb[(size_t)c * N_ + n0 + r];
    }
    if (tid < RT) xxr_s[tid] = xx[b * N_ + n0 + tid];
    __syncthreads();

    float d[RT][8];
    #pragma unroll
    for (int r = 0; r < RT; ++r)
        #pragma unroll
        for (int i = 0; i < 8; ++i) d[r][i] = 0.f;

    for (int c = 0; c < C; ++c) {
        f32x4 Q0 = *(const f32x4*)&Rc[c * 8];
        f32x4 Q1 = *(const f32x4*)&Rc[c * 8 + 4];
        const float* col = xb + (size_t)c * N_ + (tid << 3);
        f32x4 v0 = *(const f32x4*)col;
        f32x4 v1 = *(const f32x4*)(col + 4);
        #pragma unroll
        for (int i = 0; i < 4; ++i) {
            float v = v0[i];
            d[0][i] += Q0[0] * v; d[1][i] += Q0[1] * v; d[2][i] += Q0[2] * v; d[3][i] += Q0[3] * v;
            d[4][i] += Q1[0] * v; d[5][i] += Q1[1] * v; d[6][i] += Q1[2] * v; d[7][i] += Q1[3] * v;
        }
        #pragma unroll
        for (int i = 0; i < 4; ++i) {
            float v = v1[i];
            d[0][4+i] += Q0[0] * v; d[1][4+i] += Q0[1] * v; d[2][4+i] += Q0[2] * v; d[3][4+i] += Q0[3] * v;
            d[4][4+i] += Q1[0] * v; d[5][4+i] += Q1[1] * v; d[6][4+i] += Q1[2] * v; d[7][4+i] += Q1[3] * v;
        }
    }

    f32x4 xm0 = *(const f32x4*)(xx + b * N_ + (tid << 3));
    f32x4 xm1 = *(const f32x4*)(xx + b * N_ + (tid << 3) + 4);
    float xxr[RT];
    #pragma unroll
    for (int r = 0; r < RT; ++r) xxr[r] = xxr_s[r];

    int wbase = (tid << 3) + (tid >> 2);
    int rbase = ln + (ln >> 5);
    unsigned long long lower = (1ull << ln) - 1ull;
    #pragma unroll
    for (int half = 0; half < 2; ++half) {
        __syncthreads();
        #pragma unroll
        for (int rr = 0; rr < 4; ++rr) {
            int r = half * 4 + rr;
            unsigned* Dr = &DlU[rr * DLS + wbase];
            Dr[0] = key_flip(2.f * d[r][0] - xxr[r] - xm0[0]);
            Dr[1] = key_flip(2.f * d[r][1] - xxr[r] - xm0[1]);
            Dr[2] = key_flip(2.f * d[r][2] - xxr[r] - xm0[2]);
            Dr[3] = key_flip(2.f * d[r][3] - xxr[r] - xm0[3]);
            Dr[4] = key_flip(2.f * d[r][4] - xxr[r] - xm1[0]);
            Dr[5] = key_flip(2.f * d[r][5] - xxr[r] - xm1[1]);
            Dr[6] = key_flip(2.f * d[r][6] - xxr[r] - xm1[2]);
            Dr[7] = key_flip(2.f * d[r][7] - xxr[r] - xm1[3]);
        }
        __syncthreads();
        int row = half * 4 + wv;
        unsigned key[32];
        #pragma unroll
        for (int j = 0; j < 32; ++j) key[j] = DlU[wv * DLS + j * 66 + rbase];
        wave_select_emit(key, ln, lower, idxout + ((size_t)b * N_ + n0 + row) * KNN_);
    }
}

// ================= edge conv layer 1 (VALU, c-major, C=3) =================
template<int C, int O>
__global__ void edgeconv1_kernel(const float* __restrict__ src, int bstride,
                                 const float* __restrict__ W, const int* __restrict__ idx,
                                 float* __restrict__ maxh, float* __restrict__ part) {
    const int NT = 8, G = 256 / O, KT = KNN_ / G;
    __shared__ float nbr[KNN_][C];
    __shared__ float ctr[C];
    __shared__ int   jidx[KNN_];
    __shared__ float red[256];
    int tid = threadIdx.x;
    int b = blockIdx.x / (N_ / NT), n0 = (blockIdx.x % (N_ / NT)) * NT;
    int o = tid % O, sub = tid / O;
    const float* xb = src + (size_t)b * bstride;
    const float* Wl = W + (size_t)o * 2 * C;
    float ls = 0.f, lsq = 0.f;
    for (int nn = 0; nn < NT; ++nn) {
        int n = n0 + nn;
        if (tid < KNN_) jidx[tid] = idx[((size_t)b * N_ + n) * KNN_ + tid];
        __syncthreads();
        for (int t = tid; t < C; t += 256) ctr[t] = xb[t * N_ + n];
        for (int t = tid; t < KNN_ * C; t += 256) { int k = t / C, c = t % C; nbr[k][c] = xb[c * N_ + jidx[k]]; }
        __syncthreads();
        float hc = 0.f;
        for (int c = 0; c < C; ++c) hc += (Wl[C + c] - Wl[c]) * ctr[c];
        float h[KT];
        for (int i = 0; i < KT; ++i) h[i] = hc;
        for (int c = 0; c < C; ++c) { float w = Wl[c]; for (int i = 0; i < KT; ++i) h[i] += w * nbr[sub + i * G][c]; }
        float hmax = -1e30f;
        for (int i = 0; i < KT; ++i) { float v = h[i]; hmax = fmaxf(hmax, v); ls += v; lsq += v * v; }
        red[tid] = hmax; __syncthreads();
        if (sub == 0) {
            for (int s = 1; s < G; ++s) hmax = fmaxf(hmax, red[o + s * O]);
            maxh[((size_t)b * O + o) * N_ + n] = hmax;
        }
        __syncthreads();
    }
    red[tid] = ls; __syncthreads();
    if (sub == 0) for (int s = 1; s < G; ++s) ls += red[o + s * O];
    __syncthreads();
    red[tid] = lsq; __syncthreads();
    if (sub == 0) {
        for (int s = 1; s < G; ++s) lsq += red[o + s * O];
        part[((size_t)blockIdx.x * O + o) * 2 + 0] = ls;
        part[((size_t)blockIdx.x * O + o) * 2 + 1] = lsq;
    }
}

// ================= edge conv MFMA (layers 2-4), split-bf16 =================
template<int C, int O>
__global__ __launch_bounds__(256) void edge_mfma_kernel(
    const float* __restrict__ xcat, int coff,
    const unsigned short* __restrict__ Wnh, const unsigned short* __restrict__ Wnl,
    const unsigned short* __restrict__ Wdh, const unsigned short* __restrict__ Wdl,
    const int* __restrict__ idx, float* __restrict__ maxh, float* __restrict__ part) {
    const int LDA = C + 8;
    const int NKS = C / 32;
    const int OW  = O / 4;
    const int NOT = OW / 16;
    const int CPT = C / 16;
    __shared__ __align__(16) unsigned short sAh[16 * LDA];
    __shared__ __align__(16) unsigned short sAl[16 * LDA];
    __shared__ int js[16 * 20];
    int tid = threadIdx.x, ln = tid & 63, wv = tid >> 6;
    int lane15 = ln & 15, quad = ln >> 4;
    int b = blockIdx.x >> 7, n0 = (blockIdx.x & 127) * 16;
    const float* xb = xcat + (size_t)b * N_ * 512 + coff;

    for (int t = tid; t < 320; t += 256)
        js[t] = idx[((size_t)b * N_ + n0 + t / 20) * KNN_ + t % 20];

    f32x4 accMax[NOT], accSum[NOT], accSq[NOT], accHc[NOT];
    #pragma unroll
    for (int ot = 0; ot < NOT; ++ot) {
        accMax[ot] = splat4(-1e30f); accSum[ot] = splat4(0.f);
        accSq[ot] = splat4(0.f); accHc[ot] = splat4(0.f);
    }
    int srn = tid >> 4, sc0 = (tid & 15) * CPT;
    __syncthreads();

    for (int k = 0; k <= 20; ++k) {
        int j = (k < 20) ? js[srn * 20 + k] : (n0 + srn);
        const float* rp = xb + (size_t)j * 512 + sc0;
        unsigned short hi[CPT], lo[CPT];
        #pragma unroll
        for (int i4 = 0; i4 < CPT / 4; ++i4) {
            f32x4 v = *(const f32x4*)(rp + i4 * 4);
            #pragma unroll
            for (int e = 0; e < 4; ++e) {
                unsigned short h = bf16_rne(v[e]);
                hi[i4 * 4 + e] = h;
                lo[i4 * 4 + e] = bf16_rne(v[e] - bf16_f(h));
            }
        }
        __syncthreads();
        if (CPT == 8) {
            s16x8 ph, pl;
            #pragma unroll
            for (int e = 0; e < 8; ++e) { ph[e] = (short)hi[e]; pl[e] = (short)lo[e]; }
            *(s16x8*)&sAh[srn * LDA + sc0] = ph;
            *(s16x8*)&sAl[srn * LDA + sc0] = pl;
        } else {
            s16x4 ph, pl;
            #pragma unroll
            for (int e = 0; e < 4; ++e) { ph[e] = (short)hi[e]; pl[e] = (short)lo[e]; }
            *(s16x4*)&sAh[srn * LDA + sc0] = ph;
            *(s16x4*)&sAl[srn * LDA + sc0] = pl;
        }
        __syncthreads();
        s16x8 ah[NKS], al[NKS];
        #pragma unroll
        for (int ks = 0; ks < NKS; ++ks) {
            ah[ks] = *(const s16x8*)&sAh[lane15 * LDA + ks * 32 + quad * 8];
            al[ks] = *(const s16x8*)&sAl[lane15 * LDA + ks * 32 + quad * 8];
        }
        const unsigned short* Wh = (k < 20) ? Wnh : Wdh;
        const unsigned short* Wl = (k < 20) ? Wnl : Wdl;
        #pragma unroll
        for (int ot = 0; ot < NOT; ++ot) {
            int orow = wv * OW + ot * 16 + lane15;
            f32x4 dacc = splat4(0.f);
            #pragma unroll
            for (int ks = 0; ks < NKS; ++ks) {
                s16x8 bh = *(const s16x8*)&Wh[(size_t)orow * C + ks * 32 + quad * 8];
                s16x8 bl = *(const s16x8*)&Wl[(size_t)orow * C + ks * 32 + quad * 8];
                dacc = __builtin_amdgcn_mfma_f32_16x16x32_bf16(ah[ks], bh, dacc, 0, 0, 0);
                dacc = __builtin_amdgcn_mfma_f32_16x16x32_bf16(al[ks], bh, dacc, 0, 0, 0);
                dacc = __builtin_amdgcn_mfma_f32_16x16x32_bf16(ah[ks], bl, dacc, 0, 0, 0);
            }
            if (k < 20) {
                #pragma unroll
                for (int e = 0; e < 4; ++e) {
                    accMax[ot][e] = fmaxf(accMax[ot][e], dacc[e]);
                    accSum[ot][e] += dacc[e];
                    accSq[ot][e] += dacc[e] * dacc[e];
                }
            } else accHc[ot] = dacc;
        }
    }
    #pragma unroll
    for (int ot = 0; ot < NOT; ++ot) {
        int ocol = wv * OW + ot * 16 + lane15;
        float s = 0.f, q = 0.f;
        #pragma unroll
        for (int e = 0; e < 4; ++e) {
            float hc = accHc[ot][e];
            float mx = accMax[ot][e] + hc;
            float s20 = accSum[ot][e] + 20.f * hc;
            float q20 = accSq[ot][e] + 2.f * hc * accSum[ot][e] + 20.f * hc * hc;
            maxh[((size_t)b * N_ + n0 + quad * 4 + e) * O + ocol] = mx;
            s += s20; q += q20;
        }
        s += __shfl_xor(s, 16); s += __shfl_xor(s, 32);
        q += __shfl_xor(q, 16); q += __shfl_xor(q, 32);
        if (ln < 16) {
            int o = wv * OW + ot * 16 + ln;
            part[((size_t)blockIdx.x * O + o) * 2 + 0] = s;
            part[((size_t)blockIdx.x * O + o) * 2 + 1] = q;
        }
    }
}

// ================= conv1d MFMA (207/208/209), split-bf16 =================
template<int CIN, int O, bool HASB>
__global__ __launch_bounds__(256) void conv_mfma_kernel(
    const float* __restrict__ src, const unsigned short* __restrict__ Wh,
    const unsigned short* __restrict__ Wl, const float* __restrict__ bias,
    float* __restrict__ out, float* __restrict__ part) {
    const int LDA = 136;
    const int NOT = O / 16;
    __shared__ __align__(16) unsigned short sAh[64 * LDA];
    __shared__ __align__(16) unsigned short sAl[64 * LDA];
    int tid = threadIdx.x, ln = tid & 63, wv = tid >> 6;
    int lane15 = ln & 15, quad = ln >> 4;
    int b = blockIdx.x >> 5, n0 = (blockIdx.x & 31) * 64;
    const float* sb = src + ((size_t)b * N_ + n0) * CIN;

    f32x4 acc[NOT];
    #pragma unroll
    for (int ot = 0; ot < NOT; ++ot)
        acc[ot] = HASB ? splat4(bias[b * O + ot * 16 + lane15]) : splat4(0.f);

    int sr = tid >> 2, sc0 = (tid & 3) * 32;
    for (int cc = 0; cc < CIN / 128; ++cc) {
        __syncthreads();
        #pragma unroll
        for (int i4 = 0; i4 < 8; ++i4) {
            f32x4 v = *(const f32x4*)(sb + (size_t)sr * CIN + cc * 128 + sc0 + i4 * 4);
            s16x4 ph, pl;
            #pragma unroll
            for (int e = 0; e < 4; ++e) {
                unsigned short h = bf16_rne(v[e]);
                ph[e] = (short)h; pl[e] = (short)bf16_rne(v[e] - bf16_f(h));
            }
            *(s16x4*)&sAh[sr * LDA + sc0 + i4 * 4] = ph;
            *(s16x4*)&sAl[sr * LDA + sc0 + i4 * 4] = pl;
        }
        __syncthreads();
        s16x8 ah[4], al[4];
        #pragma unroll
        for (int ks = 0; ks < 4; ++ks) {
            ah[ks] = *(const s16x8*)&sAh[(wv * 16 + lane15) * LDA + ks * 32 + quad * 8];
            al[ks] = *(const s16x8*)&sAl[(wv * 16 + lane15) * LDA + ks * 32 + quad * 8];
        }
        #pragma unroll
        for (int ot = 0; ot < NOT; ++ot) {
            int orow = ot * 16 + lane15;
            const unsigned short* wrh = Wh + (size_t)orow * CIN + cc * 128;
            const unsigned short* wrl = Wl + (size_t)orow * CIN + cc * 128;
            #pragma unroll
            for (int ks = 0; ks < 4; ++ks) {
                s16x8 bh = *(const s16x8*)&wrh[ks * 32 + quad * 8];
                s16x8 bl = *(const s16x8*)&wrl[ks * 32 + quad * 8];
                acc[ot] = __builtin_amdgcn_mfma_f32_16x16x32_bf16(ah[ks], bh, acc[ot], 0, 0, 0);
                acc[ot] = __builtin_amdgcn_mfma_f32_16x16x32_bf16(al[ks], bh, acc[ot], 0, 0, 0);
                acc[ot] = __builtin_amdgcn_mfma_f32_16x16x32_bf16(ah[ks], bl, acc[ot], 0, 0, 0);
            }
        }
    }
    #pragma unroll
    for (int ot = 0; ot < NOT; ++ot) {
        int ocol = ot * 16 + lane15;
        float s = 0.f, q = 0.f;
        #pragma unroll
        for (int e = 0; e < 4; ++e) {
            float v = acc[ot][e];
            out[((size_t)b * N_ + n0 + wv * 16 + quad * 4 + e) * O + ocol] = v;
            s += v; q += v * v;
        }
        s += __shfl_xor(s, 16); s += __shfl_xor(s, 32);
        q += __shfl_xor(q, 16); q += __shfl_xor(q, 32);
        if (ln < 16) {
            part[(((size_t)blockIdx.x * 4 + wv) * O + ot * 16 + ln) * 2 + 0] = s;
            part[(((size_t)blockIdx.x * 4 + wv) * O + ot * 16 + ln) * 2 + 1] = q;
        }
    }
}

// ================= conv5 MFMA (stats + argmax tracking) =================
__global__ __launch_bounds__(256) void conv5_mfma_kernel(
    const float* __restrict__ xcat, const unsigned short* __restrict__ W5b,
    float* __restrict__ part, float* __restrict__ mpart, int* __restrict__ mipart) {
    const int LDA = 136;
    __shared__ __align__(16) unsigned short sA[16 * LDA];
    int tid = threadIdx.x, ln = tid & 63, wv = tid >> 6;
    int lane15 = ln & 15, quad = ln >> 4;
    int b = blockIdx.x >> 5, n00 = (blockIdx.x & 31) * 64;
    float sum[16], sq[16], mx[16]; int mi[16];
    #pragma unroll
    for (int ot = 0; ot < 16; ++ot) { sum[ot] = 0.f; sq[ot] = 0.f; mx[ot] = -1e30f; mi[ot] = 0; }
    int sr = tid >> 4, sc0 = (tid & 15) * 8;
    for (int mt = 0; mt < 4; ++mt) {
        int n0 = n00 + mt * 16;
        f32x4 acc[16];
        #pragma unroll
        for (int ot = 0; ot < 16; ++ot) acc[ot] = splat4(0.f);
        for (int cc = 0; cc < 4; ++cc) {
            __syncthreads();
            const float* rp = xcat + ((size_t)b * N_ + n0 + sr) * 512 + cc * 128 + sc0;
            f32x4 v0 = *(const f32x4*)(rp);
            f32x4 v1 = *(const f32x4*)(rp + 4);
            s16x8 p;
            #pragma unroll
            for (int e = 0; e < 4; ++e) { p[e] = (short)bf16_rne(v0[e]); p[4 + e] = (short)bf16_rne(v1[e]); }
            *(s16x8*)&sA[sr * LDA + sc0] = p;
            __syncthreads();
            s16x8 a[4];
            #pragma unroll
            for (int ks = 0; ks < 4; ++ks)
                a[ks] = *(const s16x8*)&sA[lane15 * LDA + ks * 32 + quad * 8];
            #pragma unroll
            for (int ot = 0; ot < 16; ++ot) {
                int orow = wv * 256 + ot * 16 + lane15;
                const unsigned short* wr = W5b + (size_t)orow * 512 + cc * 128;
                #pragma unroll
                for (int ks = 0; ks < 4; ++ks) {
                    s16x8 bh = *(const s16x8*)&wr[ks * 32 + quad * 8];
                    acc[ot] = __builtin_amdgcn_mfma_f32_16x16x32_bf16(a[ks], bh, acc[ot], 0, 0, 0);
                }
            }
        }
        #pragma unroll
        for (int ot = 0; ot < 16; ++ot) {
            #pragma unroll
            for (int e = 0; e < 4; ++e) {
                float v = acc[ot][e];
                sum[ot] += v; sq[ot] += v * v;
                if (v > mx[ot]) { mx[ot] = v; mi[ot] = n0 + quad * 4 + e; }
            }
        }
    }
    #pragma unroll
    for (int ot = 0; ot < 16; ++ot) {
        float s = sum[ot], q = sq[ot], m = mx[ot]; int im = mi[ot];
        s += __shfl_xor(s, 16); s += __shfl_xor(s, 32);
        q += __shfl_xor(q, 16); q += __shfl_xor(q, 32);
        { float m2 = __shfl_xor(m, 16); int i2 = __shfl_xor(im, 16); if (m2 > m) { m = m2; im = i2; } }
        { float m2 = __shfl_xor(m, 32); int i2 = __shfl_xor(im, 32); if (m2 > m) { m = m2; im = i2; } }
        if (ln < 16) {
            int o = wv * 256 + ot * 16 + ln;
            part[((size_t)blockIdx.x * 1024 + o) * 2 + 0] = s;
            part[((size_t)blockIdx.x * 1024 + o) * 2 + 1] = q;
            mpart[(size_t)blockIdx.x * 1024 + o] = m;
            mipart[(size_t)blockIdx.x * 1024 + o] = im;
        }
    }
}

// ================= BN stats =================
__global__ void bn_stats_kernel(const float* __restrict__ part, int nblk, int O, float count,
                                const float* __restrict__ g, const float* __restrict__ bb,
                                float* __restrict__ a, float* __restrict__ c) {
    __shared__ float s1[256], s2[256];
    int o = blockIdx.x; int tid = threadIdx.x;
    float ls = 0.f, lq = 0.f;
    for (int i = tid; i < nblk; i += 256) {
        ls += part[((size_t)i * O + o) * 2 + 0];
        lq += part[((size_t)i * O + o) * 2 + 1];
    }
    s1[tid] = ls; s2[tid] = lq; __syncthreads();
    for (int s = 128; s > 0; s >>= 1) {
        if (tid < s) { s1[tid] += s1[tid + s]; s2[tid] += s2[tid + s]; }
        __syncthreads();
    }
    if (tid == 0) {
        float mean = s1[0] / count;
        float var = fmaxf(s2[0] / count - mean * mean, 0.f);
        float scale = g[o] * rsqrtf(var + 1e-5f);
        a[o] = scale; c[o] = bb[o] - mean * scale;
    }
}

// ================= finalizes =================
__global__ void edge_fin1_kernel(const float* __restrict__ maxh, const float* __restrict__ a,
                                 const float* __restrict__ c, float* __restrict__ xcat) {
    __shared__ float t[64][33];
    int tid = threadIdx.x;
    int b = blockIdx.x >> 6, n0 = (blockIdx.x & 63) * 32;
    {
        int o = tid >> 2, g = tid & 3;
        const float* mp = maxh + ((size_t)b * 64 + o) * N_ + n0 + g * 8;
        for (int j = 0; j < 8; ++j) t[o][g * 8 + j] = mp[j];
    }
    __syncthreads();
    {
        int nl = tid >> 3, o0 = (tid & 7) * 8;
        float* op = xcat + ((size_t)b * N_ + n0 + nl) * 512 + o0;
        for (int j = 0; j < 8; ++j) {
            int o = o0 + j;
            float v = a[o] * t[o][nl] + c[o];
            op[j] = v >= 0.f ? v : 0.2f * v;
        }
    }
}

__global__ void edge_fin_rm_kernel(const float* __restrict__ maxh, const float* __restrict__ a,
                                   const float* __restrict__ c, int O, int coff,
                                   float* __restrict__ xcat) {
    int i = blockIdx.x * 256 + threadIdx.x;
    int o = i % O; size_t row = (size_t)(i / O);
    float v = a[o] * maxh[i] + c[o];
    xcat[row * 512 + coff + o] = v >= 0.f ? v : 0.2f * v;
}

// exact fp32 re-evaluation of h5 at the per-(b,o) argmax column
__global__ __launch_bounds__(256) void finalize5_exact_kernel(
    const float* __restrict__ mpart, const int* __restrict__ mipart,
    const float* __restrict__ xcat, const float* __restrict__ W5,
    const float* __restrict__ a, const float* __restrict__ c,
    float* __restrict__ glob) {
    int tid = threadIdx.x, ln = tid & 63, wv = tid >> 6;
    int p = blockIdx.x * 4 + wv;
    int b = p >> 10, o = p & 1023;
    float m = -1e30f; int mi = 0;
    if (ln < 32) {
        m = mpart[(size_t)(b * 32 + ln) * 1024 + o];
        mi = mipart[(size_t)(b * 32 + ln) * 1024 + o];
    }
    for (int off = 32; off; off >>= 1) {
        float m2 = __shfl_xor(m, off); int i2 = __shfl_xor(mi, off);
        if (m2 > m) { m = m2; mi = i2; }
    }
    const float* xr = xcat + ((size_t)b * N_ + mi) * 512 + ln * 8;
    const float* wr = W5 + (size_t)o * 512 + ln * 8;
    f32x4 x0 = *(const f32x4*)xr, x1 = *(const f32x4*)(xr + 4);
    f32x4 w0 = *(const f32x4*)wr, w1 = *(const f32x4*)(wr + 4);
    float s = x0[0] * w0[0] + x0[1] * w0[1] + x0[2] * w0[2] + x0[3] * w0[3]
            + x1[0] * w1[0] + x1[1] * w1[1] + x1[2] * w1[2] + x1[3] * w1[3];
    for (int off = 32; off; off >>= 1) s += __shfl_xor(s, off);
    if (ln == 0) {
        float v = a[o] * s + c[o];
        glob[b * 1088 + o] = v >= 0.f ? v : 0.2f * v;
    }
}

__global__ void lf_kernel(const float* __restrict__ l, const float* __restrict__ W206,
                          const float* __restrict__ g, const float* __restrict__ bb,
                          float* __restrict__ glob) {
    int tid = threadIdx.x;
    if (tid >= 64) return;
    float h[B_]; float s = 0.f, q = 0.f;
    for (int b = 0; b < B_; ++b) {
        float acc = 0.f;
        for (int c = 0; c < 16; ++c) acc += W206[tid * 16 + c] * l[b * 16 + c];
        h[b] = acc; s += acc; q += acc * acc;
    }
    float mean = s / B_;
    float var = fmaxf(q / B_ - mean * mean, 0.f);
    float scale = g[tid] * rsqrtf(var + 1e-5f);
    float off = bb[tid] - mean * scale;
    for (int b = 0; b < B_; ++b) {
        float v = scale * h[b] + off;
        glob[b * 1088 + 1024 + tid] = v >= 0.f ? v : 0.2f * v;
    }
}

__global__ void t207_kernel(const float* __restrict__ W207, const float* __restrict__ glob,
                            float* __restrict__ tbuf) {
    int b = blockIdx.x; int o = threadIdx.x;
    const float* Wr = W207 + (size_t)o * 1600;
    const float* gb = glob + b * 1088;
    float acc = 0.f;
    for (int c = 0; c < 1088; ++c) acc += Wr[c] * gb[c];
    tbuf[b * 256 + o] = acc;
}

__global__ void bn_act_rm_kernel(float* __restrict__ h, const float* __restrict__ a,
                                 const float* __restrict__ c, int O) {
    int i = blockIdx.x * 256 + threadIdx.x;
    int o = i % O;
    float v = a[o] * h[i] + c[o];
    h[i] = v >= 0.f ? v : 0.2f * v;
}

__global__ void final_rm_kernel(const float* __restrict__ src, const float* __restrict__ W,
                                float* __restrict__ out) {
    int i = blockIdx.x * 256 + threadIdx.x;
    if (i >= B_ * 50 * N_) return;
    int n = i % N_; int oc = (i / N_) % 50; int b = i / (N_ * 50);
    const float* xr = src + ((size_t)b * N_ + n) * 128;
    const float* Wr = W + oc * 128;
    float acc = 0.f;
    for (int c = 0; c < 128; c += 4) {
        f32x4 xv = *(const f32x4*)(xr + c);
        f32x4 wv = *(const f32x4*)(Wr + c);
        acc += xv[0] * wv[0] + xv[1] * wv[1] + xv[2] * wv[2] + xv[3] * wv[3];
    }
    out[i] = acc;
}

extern "C" void kernel_launch(void* const* d_in, const int* in_sizes, int n_in,
                              void* d_out, int out_size, void* d_ws, size_t ws_size,
                              hipStream_t stream) {
    const float* x     = (const float*)d_in[0];
    const float* l     = (const float*)d_in[1];
    const float* W1    = (const float*)d_in[2];
    const float* g1    = (const float*)d_in[3];
    const float* b1    = (const float*)d_in[4];
    const float* W2    = (const float*)d_in[5];
    const float* g2    = (const float*)d_in[6];
    const float* b2    = (const float*)d_in[7];
    const float* W3    = (const float*)d_in[8];
    const float* g3    = (const float*)d_in[9];
    const float* b3    = (const float*)d_in[10];
    const float* W4    = (const float*)d_in[11];
    const float* g4    = (const float*)d_in[12];
    const float* b4    = (const float*)d_in[13];
    const float* W5    = (const float*)d_in[14];
    const float* g5    = (const float*)d_in[15];
    const float* b5    = (const float*)d_in[16];
    const float* W206  = (const float*)d_in[17];
    const float* g206  = (const float*)d_in[18];
    const float* b206  = (const float*)d_in[19];
    const float* W207  = (const float*)d_in[20];
    const float* g207  = (const float*)d_in[21];
    const float* b207  = (const float*)d_in[22];
    const float* W208  = (const float*)d_in[23];
    const float* g208  = (const float*)d_in[24];
    const float* b208  = (const float*)d_in[25];
    const float* W209  = (const float*)d_in[26];
    const float* g209  = (const float*)d_in[27];
    const float* b209  = (const float*)d_in[28];
    const float* W2010 = (const float*)d_in[29];

    float* ws = (float*)d_ws;
    // ---- layout (float units), ~58.25 MB ----
    float* xcat = ws;                              // 8388608
    float* H1   = ws + 8388608;                    // 4194304 (maxh / h207 / h209 / xT)
    float* P    = ws + 12582912;                   // 1048576
    unsigned short* Wt = (unsigned short*)(ws + 13631488);  // 573440 fl
    int*   idxb = (int*)(ws + 14204928);           // 327680
    float* abuf = ws + 14532608;                   // 1024
    float* cbuf = ws + 14533632;                   // 1024
    float* glob = ws + 14534656;                   // 8704
    float* tbuf = ws + 14543360;                   // 2048
    float* xxb  = ws + 14545408;                   // 16384

    float* part5  = P;
    float* mpart5 = P + 524288;
    int*   mipart = (int*)(P + 786432);
    float* h207 = H1;
    float* h208 = xcat;
    float* h209 = H1;
    float* xT   = H1;   // overlay: dead between prev fin and edge_mfma's maxh write

    unsigned short* W2nh = Wt;            unsigned short* W2nl = Wt + 4096;
    unsigned short* W2dh = Wt + 8192;     unsigned short* W2dl = Wt + 12288;
    unsigned short* W3nh = Wt + 16384;    unsigned short* W3nl = Wt + 24576;
    unsigned short* W3dh = Wt + 32768;    unsigned short* W3dl = Wt + 40960;
    unsigned short* W4nh = Wt + 49152;    unsigned short* W4nl = Wt + 81920;
    unsigned short* W4dh = Wt + 114688;   unsigned short* W4dl = Wt + 147456;
    unsigned short* W5b  = Wt + 180224;
    unsigned short* W207h = Wt + 704512;  unsigned short* W207l = Wt + 835584;
    unsigned short* W208h = Wt + 966656;  unsigned short* W208l = Wt + 1032192;
    unsigned short* W209h = Wt + 1097728; unsigned short* W209l = Wt + 1130496;

    const float EC_CNT = (float)(B_ * N_ * KNN_);
    const float C1_CNT = (float)(B_ * N_);

    // ---- weight prep ----
    prep_edge_w<<<16, 256, 0, stream>>>(W2, W2nh, W2nl, W2dh, W2dl, 64, 64);
    prep_edge_w<<<32, 256, 0, stream>>>(W3, W3nh, W3nl, W3dh, W3dl, 128, 64);
    prep_edge_w<<<128, 256, 0, stream>>>(W4, W4nh, W4nl, W4dh, W4dl, 256, 128);
    prep_w1<<<2048, 256, 0, stream>>>(W5, W5b, 524288);
    prep_w_hl<<<512, 256, 0, stream>>>(W207, 1600, 1088, W207h, W207l, 256, 512);
    prep_w_hl<<<256, 256, 0, stream>>>(W208, 256, 0, W208h, W208l, 256, 256);
    prep_w_hl<<<128, 256, 0, stream>>>(W209, 256, 0, W209h, W209l, 128, 256);

    // ---- edge conv 1 (C=3) -> xcat cols [0,64) ----
    knn1_wl_kernel<<<2048, 256, 0, stream>>>(x, idxb);
    edgeconv1_kernel<3, 64><<<2048, 256, 0, stream>>>(x, 3 * N_, W1, idxb, H1, P);
    bn_stats_kernel<<<64, 256, 0, stream>>>(P, 2048, 64, EC_CNT, g1, b1, abuf, cbuf);
    edge_fin1_kernel<<<512, 256, 0, stream>>>(H1, abuf, cbuf, xcat);

    // ---- edge conv 2 (C=64 -> O=64) @ cols [64,128) ----
    xpose_kernel<<<256, 256, 0, stream>>>(xcat, 0, 64, xT);
    xx_kernel<<<64, 256, 0, stream>>>(xcat, 0, 64, xxb);
    knn_wl_kernel<64><<<2048, 256, 0, stream>>>(xT, xxb, idxb);
    edge_mfma_kernel<64, 64><<<1024, 256, 0, stream>>>(xcat, 0, W2nh, W2nl, W2dh, W2dl, idxb, H1, P);
    bn_stats_kernel<<<64, 256, 0, stream>>>(P, 1024, 64, EC_CNT, g2, b2, abuf, cbuf);
    edge_fin_rm_kernel<<<B_ * N_ * 64 / 256, 256, 0, stream>>>(H1, abuf, cbuf, 64, 64, xcat);

    // ---- edge conv 3 (C=64 -> O=128) @ cols [128,256) ----
    xpose_kernel<<<256, 256, 0, stream>>>(xcat, 64, 64, xT);
    xx_kernel<<<64, 256, 0, stream>>>(xcat, 64, 64, xxb);
    knn_wl_kernel<64><<<2048, 256, 0, stream>>>(xT, xxb, idxb);
    edge_mfma_kernel<64, 128><<<1024, 256, 0, stream>>>(xcat, 64, W3nh, W3nl, W3dh, W3dl, idxb, H1, P);
    bn_stats_kernel<<<128, 256, 0, stream>>>(P, 1024, 128, EC_CNT, g3, b3, abuf, cbuf);
    edge_fin_rm_kernel<<<B_ * N_ * 128 / 256, 256, 0, stream>>>(H1, abuf, cbuf, 128, 128, xcat);

    // ---- edge conv 4 (C=128 -> O=256) @ cols [256,512) ----
    xpose_kernel<<<512, 256, 0, stream>>>(xcat, 128, 128, xT);
    xx_kernel<<<64, 256, 0, stream>>>(xcat, 128, 128, xxb);
    knn_wl_kernel<128><<<2048, 256, 0, stream>>>(xT, xxb, idxb);
    edge_mfma_kernel<128, 256><<<1024, 256, 0, stream>>>(xcat, 128, W4nh, W4nl, W4dh, W4dl, idxb, H1, P);
    bn_stats_kernel<<<256, 256, 0, stream>>>(P, 1024, 256, EC_CNT, g4, b4, abuf, cbuf);
    edge_fin_rm_kernel<<<B_ * N_ * 256 / 256, 256, 0, stream>>>(H1, abuf, cbuf, 256, 256, xcat);

    // ---- conv5 (512 -> 1024) global max: bf16 stats + argmax, exact fp32 re-eval ----
    conv5_mfma_kernel<<<256, 256, 0, stream>>>(xcat, W5b, part5, mpart5, mipart);
    bn_stats_kernel<<<1024, 256, 0, stream>>>(part5, 256, 1024, C1_CNT, g5, b5, abuf, cbuf);
    lf_kernel<<<1, 64, 0, stream>>>(l, W206, g206, b206, glob);
    finalize5_exact_kernel<<<2048, 256, 0, stream>>>(mpart5, mipart, xcat, W5, abuf, cbuf, glob);
    t207_kernel<<<8, 256, 0, stream>>>(W207, glob, tbuf);

    // ---- conv 207 (512 -> 256) ----
    conv_mfma_kernel<512, 256, true><<<256, 256, 0, stream>>>(xcat, W207h, W207l, tbuf, h207, P);
    bn_stats_kernel<<<256, 256, 0, stream>>>(P, 1024, 256, C1_CNT, g207, b207, abuf, cbuf);
    bn_act_rm_kernel<<<B_ * N_ * 256 / 256, 256, 0, stream>>>(h207, abuf, cbuf, 256);

    // ---- conv 208 (256 -> 256) ----
    conv_mfma_kernel<256, 256, false><<<256, 256, 0, stream>>>(h207, W208h, W208l, nullptr, h208, P);
    bn_stats_kernel<<<256, 256, 0, stream>>>(P, 1024, 256, C1_CNT, g208, b208, abuf, cbuf);
    bn_act_rm_kernel<<<B_ * N_ * 256 / 256, 256, 0, stream>>>(h208, abuf, cbuf, 256);

    // ---- conv 209 (256 -> 128) ----
    conv_mfma_kernel<256, 128, false><<<256, 256, 0, stream>>>(h208, W209h, W209l, nullptr, h209, P);
    bn_stats_kernel<<<128, 256, 0, stream>>>(P, 1024, 128, C1_CNT, g209, b209, abuf, cbuf);
    bn_act_rm_kernel<<<B_ * N_ * 128 / 256, 256, 0, stream>>>(h209, abuf, cbuf, 128);

    // ---- final (128 -> 50), fp32 out ----
    final_rm_kernel<<<(B_ * 50 * N_ + 255) / 256, 256, 0, stream>>>(h209, W2010, (float*)d_out);
}

// Round 15
// 1232.117 us; speedup vs baseline: 1.2154x; 1.0074x over previous
//
#include <hip/hip_runtime.h>

#define B_ 8
#define N_ 2048
#define KNN_ 20
#define DLS 2112   // skewed key-row stride (words): max j*66+63+1 = 2110 < 2112

typedef __attribute__((ext_vector_type(8))) short  s16x8;
typedef __attribute__((ext_vector_type(4))) short  s16x4;
typedef __attribute__((ext_vector_type(4))) float  f32x4;

__device__ __forceinline__ unsigned short bf16_rne(float f) {
    union { float f; unsigned u; } x; x.f = f;
    unsigned r = (x.u + 0x7fffu + ((x.u >> 16) & 1u)) >> 16;
    return (unsigned short)r;
}
__device__ __forceinline__ float bf16_f(unsigned short h) {
    union { unsigned u; float f; } x; x.u = ((unsigned)h) << 16; return x.f;
}
__device__ __forceinline__ f32x4 splat4(float v) { f32x4 r; r[0]=r[1]=r[2]=r[3]=v; return r; }
__device__ __forceinline__ unsigned key_flip(float f) {
    union { float f; unsigned u; } q; q.f = f;
    return (q.u & 0x80000000u) ? ~q.u : (q.u | 0x80000000u);
}

// ================= weight prep =================
__global__ void prep_edge_w(const float* __restrict__ W, unsigned short* nh, unsigned short* nl,
                            unsigned short* dh, unsigned short* dl, int O, int C) {
    int i = blockIdx.x * 256 + threadIdx.x;
    if (i >= O * C) return;
    int o = i / C, c = i % C;
    float wn = W[(size_t)o * 2 * C + c];
    float wd = W[(size_t)o * 2 * C + C + c] - wn;
    unsigned short h1 = bf16_rne(wn); nh[i] = h1; nl[i] = bf16_rne(wn - bf16_f(h1));
    unsigned short h2 = bf16_rne(wd); dh[i] = h2; dl[i] = bf16_rne(wd - bf16_f(h2));
}
__global__ void prep_w_hl(const float* __restrict__ W, int ld, int off,
                          unsigned short* wh, unsigned short* wl, int O, int C) {
    int i = blockIdx.x * 256 + threadIdx.x;
    if (i >= O * C) return;
    int o = i / C, c = i % C;
    float w = W[(size_t)o * ld + off + c];
    unsigned short h = bf16_rne(w); wh[i] = h; wl[i] = bf16_rne(w - bf16_f(h));
}
__global__ void prep_w1(const float* __restrict__ W, unsigned short* wh, int n) {
    int i = blockIdx.x * 256 + threadIdx.x;
    if (i < n) wh[i] = bf16_rne(W[i]);
}

// ================= wave-local exact top-20 select + emit (r8-order-identical) =============
__device__ __forceinline__ void wave_select_emit(unsigned (&key)[32], int ln,
                                                 unsigned long long lower, int* __restrict__ orow) {
    unsigned T = 0u;
    bool early = false;
    for (int bit = 31; bit >= 0; --bit) {
        unsigned trial = T | (1u << bit);
        int cnt = 0;
        #pragma unroll
        for (int j = 0; j < 32; ++j)
            cnt += __popcll(__ballot(key[j] >= trial));
        if (cnt >= 20) {
            T = trial;
            if (cnt == 20) { early = true; break; }
        }
    }
    unsigned Tf = T;
    if (early) {
        unsigned mv = 0xFFFFFFFFu;
        #pragma unroll
        for (int j = 0; j < 32; ++j) {
            unsigned k = key[j];
            if (k >= T && k < mv) mv = k;
        }
        for (int off = 32; off; off >>= 1) {
            unsigned o = (unsigned)__shfl_xor((int)mv, off);
            if (o < mv) mv = o;
        }
        Tf = mv;
    }
    int base = 0;
    #pragma unroll
    for (int w = 0; w < 4; ++w) {
        #pragma unroll
        for (int j = 0; j < 8; ++j) {
            int jp = j * 4 + w;                       // r8 >T order: (w*8+j) ascending
            unsigned long long mG = __ballot(key[jp] > Tf);
            if (key[jp] > Tf) orow[base + __popcll(mG & lower)] = jp * 64 + ln;
            base += __popcll(mG);
        }
    }
    #pragma unroll
    for (int jp = 0; jp < 32; ++jp) {                 // ties: ascending index
        unsigned long long mE = __ballot(key[jp] == Tf);
        if (key[jp] == Tf) {
            int slot = base + __popcll(mE & lower);
            if (slot < 20) orow[slot] = jp * 64 + ln;
        }
        base += __popcll(mE);
    }
}

// ================= kNN layer 1 (C=3, consecutive-candidate loads, skewed keys) ==========
__global__ __launch_bounds__(256) void knn1_wl_kernel(const float* __restrict__ x,
                                                      int* __restrict__ idxout) {
    const int RT = 8;
    __shared__ unsigned DlU[4 * DLS];    // 33.8 KB, bank-skewed
    __shared__ float Rc[3][RT];
    __shared__ float xxr_s[RT];

    int tid = threadIdx.x, ln = tid & 63, wv = tid >> 6;
    int b = blockIdx.x & 7, ng = blockIdx.x >> 3;
    int n0 = ng * RT;
    const float* xb = x + (size_t)b * 3 * N_;
    if (tid < 3 * RT) { int c = tid / RT, r = tid % RT; Rc[c][r] = xb[c * N_ + n0 + r]; }
    __syncthreads();
    if (tid < RT) {
        float s = 0.f;
        for (int c = 0; c < 3; ++c) { float v = Rc[c][tid]; s += v * v; }
        xxr_s[tid] = s;
    }
    __syncthreads();

    float d[RT][8], sqv[8];
    #pragma unroll
    for (int r = 0; r < RT; ++r)
        #pragma unroll
        for (int i = 0; i < 8; ++i) d[r][i] = 0.f;
    #pragma unroll
    for (int i = 0; i < 8; ++i) sqv[i] = 0.f;

    for (int c = 0; c < 3; ++c) {
        const float* col = xb + c * N_ + (tid << 3);
        f32x4 v0 = *(const f32x4*)col;
        f32x4 v1 = *(const f32x4*)(col + 4);
        #pragma unroll
        for (int i = 0; i < 4; ++i) {
            float v = v0[i];
            sqv[i] += v * v;
            #pragma unroll
            for (int r = 0; r < RT; ++r) d[r][i] += Rc[c][r] * v;
        }
        #pragma unroll
        for (int i = 0; i < 4; ++i) {
            float v = v1[i];
            sqv[4 + i] += v * v;
            #pragma unroll
            for (int r = 0; r < RT; ++r) d[r][4 + i] += Rc[c][r] * v;
        }
    }
    float xxr[RT];
    #pragma unroll
    for (int r = 0; r < RT; ++r) xxr[r] = xxr_s[r];

    int wbase = (tid << 3) + (tid >> 2);     // skew: w(m)=m+(m>>5), m=tid*8+i
    int rbase = ln + (ln >> 5);              // read: w(j*64+ln)=j*66+ln+(ln>>5)
    unsigned long long lower = (1ull << ln) - 1ull;
    #pragma unroll
    for (int half = 0; half < 2; ++half) {
        __syncthreads();
        #pragma unroll
        for (int rr = 0; rr < 4; ++rr) {
            int r = half * 4 + rr;
            unsigned* Dr = &DlU[rr * DLS + wbase];
            #pragma unroll
            for (int i = 0; i < 8; ++i)
                Dr[i] = key_flip(2.f * d[r][i] - xxr[r] - sqv[i]);
        }
        __syncthreads();
        int row = half * 4 + wv;
        unsigned key[32];
        #pragma unroll
        for (int j = 0; j < 32; ++j) key[j] = DlU[wv * DLS + j * 66 + rbase];
        wave_select_emit(key, ln, lower, idxout + ((size_t)b * N_ + n0 + row) * KNN_);
    }
}

// ================= kNN layers 2-4 (c-major xT, f32x4 loads, skewed keys) ================
// Per-candidate key chain bit-identical to rounds 8-12.
template<int C>
__global__ __launch_bounds__(256) void knn_wl_kernel(const float* __restrict__ xT,
                                                     const float* __restrict__ xx,
                                                     int* __restrict__ idxout) {
    const int RT = 8;
    __shared__ unsigned DlU[4 * DLS];    // 33.8 KB, bank-skewed
    __shared__ float Rc[C * RT];         // c-major queries: Rc[c*8+r]
    __shared__ float xxr_s[RT];

    int tid = threadIdx.x, ln = tid & 63, wv = tid >> 6;
    int b = blockIdx.x & 7, ng = blockIdx.x >> 3;      // XCD-affinity swizzle
    int n0 = ng * RT;
    const float* xb = xT + (size_t)b * C * N_;

    for (int t = tid; t < C * RT; t += 256) {
        int c = t >> 3, r = t & 7;
        Rc[t] = xb[(size_t)c * N_ + n0 + r];
    }
    if (tid < RT) xxr_s[tid] = xx[b * N_ + n0 + tid];
    __syncthreads();

    float d[RT][8];
    #pragma unroll
    for (int r = 0; r < RT; ++r)
        #pragma unroll
        for (int i = 0; i < 8; ++i) d[r][i] = 0.f;

    for (int c = 0; c < C; ++c) {
        f32x4 Q0 = *(const f32x4*)&Rc[c * 8];
        f32x4 Q1 = *(const f32x4*)&Rc[c * 8 + 4];
        const float* col = xb + (size_t)c * N_ + (tid << 3);
        f32x4 v0 = *(const f32x4*)col;
        f32x4 v1 = *(const f32x4*)(col + 4);
        #pragma unroll
        for (int i = 0; i < 4; ++i) {
            float v = v0[i];
            d[0][i] += Q0[0] * v; d[1][i] += Q0[1] * v; d[2][i] += Q0[2] * v; d[3][i] += Q0[3] * v;
            d[4][i] += Q1[0] * v; d[5][i] += Q1[1] * v; d[6][i] += Q1[2] * v; d[7][i] += Q1[3] * v;
        }
        #pragma unroll
        for (int i = 0; i < 4; ++i) {
            float v = v1[i];
            d[0][4+i] += Q0[0] * v; d[1][4+i] += Q0[1] * v; d[2][4+i] += Q0[2] * v; d[3][4+i] += Q0[3] * v;
            d[4][4+i] += Q1[0] * v; d[5][4+i] += Q1[1] * v; d[6][4+i] += Q1[2] * v; d[7][4+i] += Q1[3] * v;
        }
    }

    f32x4 xm0 = *(const f32x4*)(xx + b * N_ + (tid << 3));
    f32x4 xm1 = *(const f32x4*)(xx + b * N_ + (tid << 3) + 4);
    float xxr[RT];
    #pragma unroll
    for (int r = 0; r < RT; ++r) xxr[r] = xxr_s[r];

    int wbase = (tid << 3) + (tid >> 2);
    int rbase = ln + (ln >> 5);
    unsigned long long lower = (1ull << ln) - 1ull;
    #pragma unroll
    for (int half = 0; half < 2; ++half) {
        __syncthreads();
        #pragma unroll
        for (int rr = 0; rr < 4; ++rr) {
            int r = half * 4 + rr;
            unsigned* Dr = &DlU[rr * DLS + wbase];
            Dr[0] = key_flip(2.f * d[r][0] - xxr[r] - xm0[0]);
            Dr[1] = key_flip(2.f * d[r][1] - xxr[r] - xm0[1]);
            Dr[2] = key_flip(2.f * d[r][2] - xxr[r] - xm0[2]);
            Dr[3] = key_flip(2.f * d[r][3] - xxr[r] - xm0[3]);
            Dr[4] = key_flip(2.f * d[r][4] - xxr[r] - xm1[0]);
            Dr[5] = key_flip(2.f * d[r][5] - xxr[r] - xm1[1]);
            Dr[6] = key_flip(2.f * d[r][6] - xxr[r] - xm1[2]);
            Dr[7] = key_flip(2.f * d[r][7] - xxr[r] - xm1[3]);
        }
        __syncthreads();
        int row = half * 4 + wv;
        unsigned key[32];
        #pragma unroll
        for (int j = 0; j < 32; ++j) key[j] = DlU[wv * DLS + j * 66 + rbase];
        wave_select_emit(key, ln, lower, idxout + ((size_t)b * N_ + n0 + row) * KNN_);
    }
}

// ================= edge conv layer 1 (VALU, c-major, C=3) =================
template<int C, int O>
__global__ void edgeconv1_kernel(const float* __restrict__ src, int bstride,
                                 const float* __restrict__ W, const int* __restrict__ idx,
                                 float* __restrict__ maxh, float* __restrict__ part) {
    const int NT = 8, G = 256 / O, KT = KNN_ / G;
    __shared__ float nbr[KNN_][C];
    __shared__ float ctr[C];
    __shared__ int   jidx[KNN_];
    __shared__ float red[256];
    int tid = threadIdx.x;
    int b = blockIdx.x / (N_ / NT), n0 = (blockIdx.x % (N_ / NT)) * NT;
    int o = tid % O, sub = tid / O;
    const float* xb = src + (size_t)b * bstride;
    const float* Wl = W + (size_t)o * 2 * C;
    float ls = 0.f, lsq = 0.f;
    for (int nn = 0; nn < NT; ++nn) {
        int n = n0 + nn;
        if (tid < KNN_) jidx[tid] = idx[((size_t)b * N_ + n) * KNN_ + tid];
        __syncthreads();
        for (int t = tid; t < C; t += 256) ctr[t] = xb[t * N_ + n];
        for (int t = tid; t < KNN_ * C; t += 256) { int k = t / C, c = t % C; nbr[k][c] = xb[c * N_ + jidx[k]]; }
        __syncthreads();
        float hc = 0.f;
        for (int c = 0; c < C; ++c) hc += (Wl[C + c] - Wl[c]) * ctr[c];
        float h[KT];
        for (int i = 0; i < KT; ++i) h[i] = hc;
        for (int c = 0; c < C; ++c) { float w = Wl[c]; for (int i = 0; i < KT; ++i) h[i] += w * nbr[sub + i * G][c]; }
        float hmax = -1e30f;
        for (int i = 0; i < KT; ++i) { float v = h[i]; hmax = fmaxf(hmax, v); ls += v; lsq += v * v; }
        red[tid] = hmax; __syncthreads();
        if (sub == 0) {
            for (int s = 1; s < G; ++s) hmax = fmaxf(hmax, red[o + s * O]);
            maxh[((size_t)b * O + o) * N_ + n] = hmax;
        }
        __syncthreads();
    }
    red[tid] = ls; __syncthreads();
    if (sub == 0) for (int s = 1; s < G; ++s) ls += red[o + s * O];
    __syncthreads();
    red[tid] = lsq; __syncthreads();
    if (sub == 0) {
        for (int s = 1; s < G; ++s) lsq += red[o + s * O];
        part[((size_t)blockIdx.x * O + o) * 2 + 0] = ls;
        part[((size_t)blockIdx.x * O + o) * 2 + 1] = lsq;
    }
}

// ================= edge conv MFMA (layers 2-4), split-bf16 =================
template<int C, int O>
__global__ __launch_bounds__(256) void edge_mfma_kernel(
    const float* __restrict__ xcat, int coff,
    const unsigned short* __restrict__ Wnh, const unsigned short* __restrict__ Wnl,
    const unsigned short* __restrict__ Wdh, const unsigned short* __restrict__ Wdl,
    const int* __restrict__ idx, float* __restrict__ maxh, float* __restrict__ part) {
    const int LDA = C + 8;
    const int NKS = C / 32;
    const int OW  = O / 4;
    const int NOT = OW / 16;
    const int CPT = C / 16;
    __shared__ __align__(16) unsigned short sAh[16 * LDA];
    __shared__ __align__(16) unsigned short sAl[16 * LDA];
    __shared__ int js[16 * 20];
    int tid = threadIdx.x, ln = tid & 63, wv = tid >> 6;
    int lane15 = ln & 15, quad = ln >> 4;
    int b = blockIdx.x >> 7, n0 = (blockIdx.x & 127) * 16;
    const float* xb = xcat + (size_t)b * N_ * 512 + coff;

    for (int t = tid; t < 320; t += 256)
        js[t] = idx[((size_t)b * N_ + n0 + t / 20) * KNN_ + t % 20];

    f32x4 accMax[NOT], accSum[NOT], accSq[NOT], accHc[NOT];
    #pragma unroll
    for (int ot = 0; ot < NOT; ++ot) {
        accMax[ot] = splat4(-1e30f); accSum[ot] = splat4(0.f);
        accSq[ot] = splat4(0.f); accHc[ot] = splat4(0.f);
    }
    int srn = tid >> 4, sc0 = (tid & 15) * CPT;
    __syncthreads();

    for (int k = 0; k <= 20; ++k) {
        int j = (k < 20) ? js[srn * 20 + k] : (n0 + srn);
        const float* rp = xb + (size_t)j * 512 + sc0;
        unsigned short hi[CPT], lo[CPT];
        #pragma unroll
        for (int i4 = 0; i4 < CPT / 4; ++i4) {
            f32x4 v = *(const f32x4*)(rp + i4 * 4);
            #pragma unroll
            for (int e = 0; e < 4; ++e) {
                unsigned short h = bf16_rne(v[e]);
                hi[i4 * 4 + e] = h;
                lo[i4 * 4 + e] = bf16_rne(v[e] - bf16_f(h));
            }
        }
        __syncthreads();
        if (CPT == 8) {
            s16x8 ph, pl;
            #pragma unroll
            for (int e = 0; e < 8; ++e) { ph[e] = (short)hi[e]; pl[e] = (short)lo[e]; }
            *(s16x8*)&sAh[srn * LDA + sc0] = ph;
            *(s16x8*)&sAl[srn * LDA + sc0] = pl;
        } else {
            s16x4 ph, pl;
            #pragma unroll
            for (int e = 0; e < 4; ++e) { ph[e] = (short)hi[e]; pl[e] = (short)lo[e]; }
            *(s16x4*)&sAh[srn * LDA + sc0] = ph;
            *(s16x4*)&sAl[srn * LDA + sc0] = pl;
        }
        __syncthreads();
        s16x8 ah[NKS], al[NKS];
        #pragma unroll
        for (int ks = 0; ks < NKS; ++ks) {
            ah[ks] = *(const s16x8*)&sAh[lane15 * LDA + ks * 32 + quad * 8];
            al[ks] = *(const s16x8*)&sAl[lane15 * LDA + ks * 32 + quad * 8];
        }
        const unsigned short* Wh = (k < 20) ? Wnh : Wdh;
        const unsigned short* Wl = (k < 20) ? Wnl : Wdl;
        #pragma unroll
        for (int ot = 0; ot < NOT; ++ot) {
            int orow = wv * OW + ot * 16 + lane15;
            f32x4 dacc = splat4(0.f);
            #pragma unroll
            for (int ks = 0; ks < NKS; ++ks) {
                s16x8 bh = *(const s16x8*)&Wh[(size_t)orow * C + ks * 32 + quad * 8];
                s16x8 bl = *(const s16x8*)&Wl[(size_t)orow * C + ks * 32 + quad * 8];
                dacc = __builtin_amdgcn_mfma_f32_16x16x32_bf16(ah[ks], bh, dacc, 0, 0, 0);
                dacc = __builtin_amdgcn_mfma_f32_16x16x32_bf16(al[ks], bh, dacc, 0, 0, 0);
                dacc = __builtin_amdgcn_mfma_f32_16x16x32_bf16(ah[ks], bl, dacc, 0, 0, 0);
            }
            if (k < 20) {
                #pragma unroll
                for (int e = 0; e < 4; ++e) {
                    accMax[ot][e] = fmaxf(accMax[ot][e], dacc[e]);
                    accSum[ot][e] += dacc[e];
                    accSq[ot][e] += dacc[e] * dacc[e];
                }
            } else accHc[ot] = dacc;
        }
    }
    #pragma unroll
    for (int ot = 0; ot < NOT; ++ot) {
        int ocol = wv * OW + ot * 16 + lane15;
        float s = 0.f, q = 0.f;
        #pragma unroll
        for (int e = 0; e < 4; ++e) {
            float hc = accHc[ot][e];
            float mx = accMax[ot][e] + hc;
            float s20 = accSum[ot][e] + 20.f * hc;
            float q20 = accSq[ot][e] + 2.f * hc * accSum[ot][e] + 20.f * hc * hc;
            maxh[((size_t)b * N_ + n0 + quad * 4 + e) * O + ocol] = mx;
            s += s20; q += q20;
        }
        s += __shfl_xor(s, 16); s += __shfl_xor(s, 32);
        q += __shfl_xor(q, 16); q += __shfl_xor(q, 32);
        if (ln < 16) {
            int o = wv * OW + ot * 16 + ln;
            part[((size_t)blockIdx.x * O + o) * 2 + 0] = s;
            part[((size_t)blockIdx.x * O + o) * 2 + 1] = q;
        }
    }
}

// ================= conv1d MFMA (207/208/209), split-bf16 =================
template<int CIN, int O, bool HASB>
__global__ __launch_bounds__(256) void conv_mfma_kernel(
    const float* __restrict__ src, const unsigned short* __restrict__ Wh,
    const unsigned short* __restrict__ Wl, const float* __restrict__ bias,
    float* __restrict__ out, float* __restrict__ part) {
    const int LDA = 136;
    const int NOT = O / 16;
    __shared__ __align__(16) unsigned short sAh[64 * LDA];
    __shared__ __align__(16) unsigned short sAl[64 * LDA];
    int tid = threadIdx.x, ln = tid & 63, wv = tid >> 6;
    int lane15 = ln & 15, quad = ln >> 4;
    int b = blockIdx.x >> 5, n0 = (blockIdx.x & 31) * 64;
    const float* sb = src + ((size_t)b * N_ + n0) * CIN;

    f32x4 acc[NOT];
    #pragma unroll
    for (int ot = 0; ot < NOT; ++ot)
        acc[ot] = HASB ? splat4(bias[b * O + ot * 16 + lane15]) : splat4(0.f);

    int sr = tid >> 2, sc0 = (tid & 3) * 32;
    for (int cc = 0; cc < CIN / 128; ++cc) {
        __syncthreads();
        #pragma unroll
        for (int i4 = 0; i4 < 8; ++i4) {
            f32x4 v = *(const f32x4*)(sb + (size_t)sr * CIN + cc * 128 + sc0 + i4 * 4);
            s16x4 ph, pl;
            #pragma unroll
            for (int e = 0; e < 4; ++e) {
                unsigned short h = bf16_rne(v[e]);
                ph[e] = (short)h; pl[e] = (short)bf16_rne(v[e] - bf16_f(h));
            }
            *(s16x4*)&sAh[sr * LDA + sc0 + i4 * 4] = ph;
            *(s16x4*)&sAl[sr * LDA + sc0 + i4 * 4] = pl;
        }
        __syncthreads();
        s16x8 ah[4], al[4];
        #pragma unroll
        for (int ks = 0; ks < 4; ++ks) {
            ah[ks] = *(const s16x8*)&sAh[(wv * 16 + lane15) * LDA + ks * 32 + quad * 8];
            al[ks] = *(const s16x8*)&sAl[(wv * 16 + lane15) * LDA + ks * 32 + quad * 8];
        }
        #pragma unroll
        for (int ot = 0; ot < NOT; ++ot) {
            int orow = ot * 16 + lane15;
            const unsigned short* wrh = Wh + (size_t)orow * CIN + cc * 128;
            const unsigned short* wrl = Wl + (size_t)orow * CIN + cc * 128;
            #pragma unroll
            for (int ks = 0; ks < 4; ++ks) {
                s16x8 bh = *(const s16x8*)&wrh[ks * 32 + quad * 8];
                s16x8 bl = *(const s16x8*)&wrl[ks * 32 + quad * 8];
                acc[ot] = __builtin_amdgcn_mfma_f32_16x16x32_bf16(ah[ks], bh, acc[ot], 0, 0, 0);
                acc[ot] = __builtin_amdgcn_mfma_f32_16x16x32_bf16(al[ks], bh, acc[ot], 0, 0, 0);
                acc[ot] = __builtin_amdgcn_mfma_f32_16x16x32_bf16(ah[ks], bl, acc[ot], 0, 0, 0);
            }
        }
    }
    #pragma unroll
    for (int ot = 0; ot < NOT; ++ot) {
        int ocol = ot * 16 + lane15;
        float s = 0.f, q = 0.f;
        #pragma unroll
        for (int e = 0; e < 4; ++e) {
            float v = acc[ot][e];
            out[((size_t)b * N_ + n0 + wv * 16 + quad * 4 + e) * O + ocol] = v;
            s += v; q += v * v;
        }
        s += __shfl_xor(s, 16); s += __shfl_xor(s, 32);
        q += __shfl_xor(q, 16); q += __shfl_xor(q, 32);
        if (ln < 16) {
            part[(((size_t)blockIdx.x * 4 + wv) * O + ot * 16 + ln) * 2 + 0] = s;
            part[(((size_t)blockIdx.x * 4 + wv) * O + ot * 16 + ln) * 2 + 1] = q;
        }
    }
}

// ================= conv5 MFMA (stats + argmax tracking) =================
__global__ __launch_bounds__(256) void conv5_mfma_kernel(
    const float* __restrict__ xcat, const unsigned short* __restrict__ W5b,
    float* __restrict__ part, float* __restrict__ mpart, int* __restrict__ mipart) {
    const int LDA = 136;
    __shared__ __align__(16) unsigned short sA[16 * LDA];
    int tid = threadIdx.x, ln = tid & 63, wv = tid >> 6;
    int lane15 = ln & 15, quad = ln >> 4;
    int b = blockIdx.x >> 5, n00 = (blockIdx.x & 31) * 64;
    float sum[16], sq[16], mx[16]; int mi[16];
    #pragma unroll
    for (int ot = 0; ot < 16; ++ot) { sum[ot] = 0.f; sq[ot] = 0.f; mx[ot] = -1e30f; mi[ot] = 0; }
    int sr = tid >> 4, sc0 = (tid & 15) * 8;
    for (int mt = 0; mt < 4; ++mt) {
        int n0 = n00 + mt * 16;
        f32x4 acc[16];
        #pragma unroll
        for (int ot = 0; ot < 16; ++ot) acc[ot] = splat4(0.f);
        for (int cc = 0; cc < 4; ++cc) {
            __syncthreads();
            const float* rp = xcat + ((size_t)b * N_ + n0 + sr) * 512 + cc * 128 + sc0;
            f32x4 v0 = *(const f32x4*)(rp);
            f32x4 v1 = *(const f32x4*)(rp + 4);
            s16x8 p;
            #pragma unroll
            for (int e = 0; e < 4; ++e) { p[e] = (short)bf16_rne(v0[e]); p[4 + e] = (short)bf16_rne(v1[e]); }
            *(s16x8*)&sA[sr * LDA + sc0] = p;
            __syncthreads();
            s16x8 a[4];
            #pragma unroll
            for (int ks = 0; ks < 4; ++ks)
                a[ks] = *(const s16x8*)&sA[lane15 * LDA + ks * 32 + quad * 8];
            #pragma unroll
            for (int ot = 0; ot < 16; ++ot) {
                int orow = wv * 256 + ot * 16 + lane15;
                const unsigned short* wr = W5b + (size_t)orow * 512 + cc * 128;
                #pragma unroll
                for (int ks = 0; ks < 4; ++ks) {
                    s16x8 bh = *(const s16x8*)&wr[ks * 32 + quad * 8];
                    acc[ot] = __builtin_amdgcn_mfma_f32_16x16x32_bf16(a[ks], bh, acc[ot], 0, 0, 0);
                }
            }
        }
        #pragma unroll
        for (int ot = 0; ot < 16; ++ot) {
            #pragma unroll
            for (int e = 0; e < 4; ++e) {
                float v = acc[ot][e];
                sum[ot] += v; sq[ot] += v * v;
                if (v > mx[ot]) { mx[ot] = v; mi[ot] = n0 + quad * 4 + e; }
            }
        }
    }
    #pragma unroll
    for (int ot = 0; ot < 16; ++ot) {
        float s = sum[ot], q = sq[ot], m = mx[ot]; int im = mi[ot];
        s += __shfl_xor(s, 16); s += __shfl_xor(s, 32);
        q += __shfl_xor(q, 16); q += __shfl_xor(q, 32);
        { float m2 = __shfl_xor(m, 16); int i2 = __shfl_xor(im, 16); if (m2 > m) { m = m2; im = i2; } }
        { float m2 = __shfl_xor(m, 32); int i2 = __shfl_xor(im, 32); if (m2 > m) { m = m2; im = i2; } }
        if (ln < 16) {
            int o = wv * 256 + ot * 16 + ln;
            part[((size_t)blockIdx.x * 1024 + o) * 2 + 0] = s;
            part[((size_t)blockIdx.x * 1024 + o) * 2 + 1] = q;
            mpart[(size_t)blockIdx.x * 1024 + o] = m;
            mipart[(size_t)blockIdx.x * 1024 + o] = im;
        }
    }
}

// ================= BN stats =================
__global__ void bn_stats_kernel(const float* __restrict__ part, int nblk, int O, float count,
                                const float* __restrict__ g, const float* __restrict__ bb,
                                float* __restrict__ a, float* __restrict__ c) {
    __shared__ float s1[256], s2[256];
    int o = blockIdx.x; int tid = threadIdx.x;
    float ls = 0.f, lq = 0.f;
    for (int i = tid; i < nblk; i += 256) {
        ls += part[((size_t)i * O + o) * 2 + 0];
        lq += part[((size_t)i * O + o) * 2 + 1];
    }
    s1[tid] = ls; s2[tid] = lq; __syncthreads();
    for (int s = 128; s > 0; s >>= 1) {
        if (tid < s) { s1[tid] += s1[tid + s]; s2[tid] += s2[tid + s]; }
        __syncthreads();
    }
    if (tid == 0) {
        float mean = s1[0] / count;
        float var = fmaxf(s2[0] / count - mean * mean, 0.f);
        float scale = g[o] * rsqrtf(var + 1e-5f);
        a[o] = scale; c[o] = bb[o] - mean * scale;
    }
}

// ================= fused finalize layer 1: maxh1 [o][n] -> xcat cols[0,64) + xT + xx =====
// v identical to old edge_fin1; xx = single sequential chain ascending o (== xx_kernel chain).
__global__ __launch_bounds__(256) void fin_fuse1_kernel(
    const float* __restrict__ maxh1, const float* __restrict__ a, const float* __restrict__ c,
    float* __restrict__ xcat, float* __restrict__ xT, float* __restrict__ xx) {
    __shared__ float t[64][65];
    int tid = threadIdx.x;
    int b = blockIdx.x >> 5, n0 = (blockIdx.x & 31) * 64;
    #pragma unroll
    for (int k = 0; k < 16; ++k) {
        int idx = k * 256 + tid;
        int ol = idx >> 6, nl = idx & 63;
        float m = maxh1[((size_t)b * 64 + ol) * N_ + n0 + nl];
        float v = a[ol] * m + c[ol];
        v = v >= 0.f ? v : 0.2f * v;
        t[ol][nl] = v;
        xT[((size_t)b * 64 + ol) * N_ + n0 + nl] = v;
    }
    __syncthreads();
    #pragma unroll
    for (int k = 0; k < 16; ++k) {
        int idx = k * 256 + tid;
        int nl = idx >> 6, ol = idx & 63;
        xcat[((size_t)b * N_ + n0 + nl) * 512 + ol] = t[ol][nl];
    }
    if (tid < 64) {
        float s = 0.f;
        for (int ol = 0; ol < 64; ++ol) { float v = t[ol][tid]; s += v * v; }
        xx[b * N_ + n0 + tid] = s;
    }
}

// ===== fused finalize layers 2-3: maxh [n][O] -> xcat cols[coff,coff+O) + xT + xx =======
template<int O>
__global__ __launch_bounds__(256) void fin_fuse_rm_kernel(
    const float* __restrict__ maxh, const float* __restrict__ a, const float* __restrict__ c,
    int coff, float* __restrict__ xcat, float* __restrict__ xT, float* __restrict__ xx) {
    __shared__ float t[64][65];
    int tid = threadIdx.x;
    int b = blockIdx.x >> 5, n0 = (blockIdx.x & 31) * 64;
    float s = 0.f;                     // per-row xx chain (thread tid<64 owns row n0+tid)
    for (int oc = 0; oc < O; oc += 64) {
        __syncthreads();
        #pragma unroll
        for (int k = 0; k < 16; ++k) {
            int idx = k * 256 + tid;
            int nl = idx >> 6, ol = idx & 63;
            float m = maxh[((size_t)b * N_ + n0 + nl) * O + oc + ol];
            float v = a[oc + ol] * m + c[oc + ol];
            v = v >= 0.f ? v : 0.2f * v;
            t[nl][ol] = v;
            xcat[((size_t)b * N_ + n0 + nl) * 512 + coff + oc + ol] = v;
        }
        __syncthreads();
        #pragma unroll
        for (int k = 0; k < 16; ++k) {
            int idx = k * 256 + tid;
            int ol = idx >> 6, nl = idx & 63;
            xT[((size_t)b * O + oc + ol) * N_ + n0 + nl] = t[nl][ol];
        }
        if (tid < 64) {
            for (int ol = 0; ol < 64; ++ol) { float v = t[tid][ol]; s += v * v; }
        }
    }
    if (tid < 64) xx[b * N_ + n0 + tid] = s;
}

// ================= plain finalize (layer 4, no kNN consumer) =================
__global__ void edge_fin_rm_kernel(const float* __restrict__ maxh, const float* __restrict__ a,
                                   const float* __restrict__ c, int O, int coff,
                                   float* __restrict__ xcat) {
    int i = blockIdx.x * 256 + threadIdx.x;
    int o = i % O; size_t row = (size_t)(i / O);
    float v = a[o] * maxh[i] + c[o];
    xcat[row * 512 + coff + o] = v >= 0.f ? v : 0.2f * v;
}

// exact fp32 re-evaluation of h5 at the per-(b,o) argmax column
__global__ __launch_bounds__(256) void finalize5_exact_kernel(
    const float* __restrict__ mpart, const int* __restrict__ mipart,
    const float* __restrict__ xcat, const float* __restrict__ W5,
    const float* __restrict__ a, const float* __restrict__ c,
    float* __restrict__ glob) {
    int tid = threadIdx.x, ln = tid & 63, wv = tid >> 6;
    int p = blockIdx.x * 4 + wv;
    int b = p >> 10, o = p & 1023;
    float m = -1e30f; int mi = 0;
    if (ln < 32) {
        m = mpart[(size_t)(b * 32 + ln) * 1024 + o];
        mi = mipart[(size_t)(b * 32 + ln) * 1024 + o];
    }
    for (int off = 32; off; off >>= 1) {
        float m2 = __shfl_xor(m, off); int i2 = __shfl_xor(mi, off);
        if (m2 > m) { m = m2; mi = i2; }
    }
    const float* xr = xcat + ((size_t)b * N_ + mi) * 512 + ln * 8;
    const float* wr = W5 + (size_t)o * 512 + ln * 8;
    f32x4 x0 = *(const f32x4*)xr, x1 = *(const f32x4*)(xr + 4);
    f32x4 w0 = *(const f32x4*)wr, w1 = *(const f32x4*)(wr + 4);
    float s = x0[0] * w0[0] + x0[1] * w0[1] + x0[2] * w0[2] + x0[3] * w0[3]
            + x1[0] * w1[0] + x1[1] * w1[1] + x1[2] * w1[2] + x1[3] * w1[3];
    for (int off = 32; off; off >>= 1) s += __shfl_xor(s, off);
    if (ln == 0) {
        float v = a[o] * s + c[o];
        glob[b * 1088 + o] = v >= 0.f ? v : 0.2f * v;
    }
}

__global__ void lf_kernel(const float* __restrict__ l, const float* __restrict__ W206,
                          const float* __restrict__ g, const float* __restrict__ bb,
                          float* __restrict__ glob) {
    int tid = threadIdx.x;
    if (tid >= 64) return;
    float h[B_]; float s = 0.f, q = 0.f;
    for (int b = 0; b < B_; ++b) {
        float acc = 0.f;
        for (int c = 0; c < 16; ++c) acc += W206[tid * 16 + c] * l[b * 16 + c];
        h[b] = acc; s += acc; q += acc * acc;
    }
    float mean = s / B_;
    float var = fmaxf(q / B_ - mean * mean, 0.f);
    float scale = g[tid] * rsqrtf(var + 1e-5f);
    float off = bb[tid] - mean * scale;
    for (int b = 0; b < B_; ++b) {
        float v = scale * h[b] + off;
        glob[b * 1088 + 1024 + tid] = v >= 0.f ? v : 0.2f * v;
    }
}

__global__ void t207_kernel(const float* __restrict__ W207, const float* __restrict__ glob,
                            float* __restrict__ tbuf) {
    int b = blockIdx.x; int o = threadIdx.x;
    const float* Wr = W207 + (size_t)o * 1600;
    const float* gb = glob + b * 1088;
    float acc = 0.f;
    for (int c = 0; c < 1088; ++c) acc += Wr[c] * gb[c];
    tbuf[b * 256 + o] = acc;
}

__global__ void bn_act_rm_kernel(float* __restrict__ h, const float* __restrict__ a,
                                 const float* __restrict__ c, int O) {
    int i = blockIdx.x * 256 + threadIdx.x;
    int o = i % O;
    float v = a[o] * h[i] + c[o];
    h[i] = v >= 0.f ? v : 0.2f * v;
}

__global__ void final_rm_kernel(const float* __restrict__ src, const float* __restrict__ W,
                                float* __restrict__ out) {
    int i = blockIdx.x * 256 + threadIdx.x;
    if (i >= B_ * 50 * N_) return;
    int n = i % N_; int oc = (i / N_) % 50; int b = i / (N_ * 50);
    const float* xr = src + ((size_t)b * N_ + n) * 128;
    const float* Wr = W + oc * 128;
    float acc = 0.f;
    for (int c = 0; c < 128; c += 4) {
        f32x4 xv = *(const f32x4*)(xr + c);
        f32x4 wv = *(const f32x4*)(Wr + c);
        acc += xv[0] * wv[0] + xv[1] * wv[1] + xv[2] * wv[2] + xv[3] * wv[3];
    }
    out[i] = acc;
}

extern "C" void kernel_launch(void* const* d_in, const int* in_sizes, int n_in,
                              void* d_out, int out_size, void* d_ws, size_t ws_size,
                              hipStream_t stream) {
    const float* x     = (const float*)d_in[0];
    const float* l     = (const float*)d_in[1];
    const float* W1    = (const float*)d_in[2];
    const float* g1    = (const float*)d_in[3];
    const float* b1    = (const float*)d_in[4];
    const float* W2    = (const float*)d_in[5];
    const float* g2    = (const float*)d_in[6];
    const float* b2    = (const float*)d_in[7];
    const float* W3    = (const float*)d_in[8];
    const float* g3    = (const float*)d_in[9];
    const float* b3    = (const float*)d_in[10];
    const float* W4    = (const float*)d_in[11];
    const float* g4    = (const float*)d_in[12];
    const float* b4    = (const float*)d_in[13];
    const float* W5    = (const float*)d_in[14];
    const float* g5    = (const float*)d_in[15];
    const float* b5    = (const float*)d_in[16];
    const float* W206  = (const float*)d_in[17];
    const float* g206  = (const float*)d_in[18];
    const float* b206  = (const float*)d_in[19];
    const float* W207  = (const float*)d_in[20];
    const float* g207  = (const float*)d_in[21];
    const float* b207  = (const float*)d_in[22];
    const float* W208  = (const float*)d_in[23];
    const float* g208  = (const float*)d_in[24];
    const float* b208  = (const float*)d_in[25];
    const float* W209  = (const float*)d_in[26];
    const float* g209  = (const float*)d_in[27];
    const float* b209  = (const float*)d_in[28];
    const float* W2010 = (const float*)d_in[29];

    float* ws = (float*)d_ws;
    // ---- layout (float units), ~58.25 MB ----
    float* xcat = ws;                              // 8388608
    float* H1   = ws + 8388608;                    // 4194304 (maxh / h207 / h209; xT at +2M)
    float* P    = ws + 12582912;                   // 1048576
    unsigned short* Wt = (unsigned short*)(ws + 13631488);  // 573440 fl
    int*   idxb = (int*)(ws + 14204928);           // 327680
    float* abuf = ws + 14532608;                   // 1024
    float* cbuf = ws + 14533632;                   // 1024
    float* glob = ws + 14534656;                   // 8704
    float* tbuf = ws + 14543360;                   // 2048
    float* xxb  = ws + 14545408;                   // 16384

    float* part5  = P;
    float* mpart5 = P + 524288;
    int*   mipart = (int*)(P + 786432);
    float* h207 = H1;
    float* h208 = xcat;
    float* h209 = H1;
    // xT overlay: upper half of H1. maxh for layers 1-3 occupies <= 2M fl at H1 base;
    // xT (<= 2M fl) at H1+2M is disjoint; consumed by kNN before the next edge_mfma
    // overwrites H1 (stream-ordered).
    float* xT = H1 + 2097152;

    unsigned short* W2nh = Wt;            unsigned short* W2nl = Wt + 4096;
    unsigned short* W2dh = Wt + 8192;     unsigned short* W2dl = Wt + 12288;
    unsigned short* W3nh = Wt + 16384;    unsigned short* W3nl = Wt + 24576;
    unsigned short* W3dh = Wt + 32768;    unsigned short* W3dl = Wt + 40960;
    unsigned short* W4nh = Wt + 49152;    unsigned short* W4nl = Wt + 81920;
    unsigned short* W4dh = Wt + 114688;   unsigned short* W4dl = Wt + 147456;
    unsigned short* W5b  = Wt + 180224;
    unsigned short* W207h = Wt + 704512;  unsigned short* W207l = Wt + 835584;
    unsigned short* W208h = Wt + 966656;  unsigned short* W208l = Wt + 1032192;
    unsigned short* W209h = Wt + 1097728; unsigned short* W209l = Wt + 1130496;

    const float EC_CNT = (float)(B_ * N_ * KNN_);
    const float C1_CNT = (float)(B_ * N_);

    // ---- weight prep ----
    prep_edge_w<<<16, 256, 0, stream>>>(W2, W2nh, W2nl, W2dh, W2dl, 64, 64);
    prep_edge_w<<<32, 256, 0, stream>>>(W3, W3nh, W3nl, W3dh, W3dl, 128, 64);
    prep_edge_w<<<128, 256, 0, stream>>>(W4, W4nh, W4nl, W4dh, W4dl, 256, 128);
    prep_w1<<<2048, 256, 0, stream>>>(W5, W5b, 524288);
    prep_w_hl<<<512, 256, 0, stream>>>(W207, 1600, 1088, W207h, W207l, 256, 512);
    prep_w_hl<<<256, 256, 0, stream>>>(W208, 256, 0, W208h, W208l, 256, 256);
    prep_w_hl<<<128, 256, 0, stream>>>(W209, 256, 0, W209h, W209l, 128, 256);

    // ---- edge conv 1 (C=3) -> xcat cols [0,64) + xT + xx (fused) ----
    knn1_wl_kernel<<<2048, 256, 0, stream>>>(x, idxb);
    edgeconv1_kernel<3, 64><<<2048, 256, 0, stream>>>(x, 3 * N_, W1, idxb, H1, P);
    bn_stats_kernel<<<64, 256, 0, stream>>>(P, 2048, 64, EC_CNT, g1, b1, abuf, cbuf);
    fin_fuse1_kernel<<<256, 256, 0, stream>>>(H1, abuf, cbuf, xcat, xT, xxb);

    // ---- edge conv 2 (C=64 -> O=64) @ cols [64,128) ----
    knn_wl_kernel<64><<<2048, 256, 0, stream>>>(xT, xxb, idxb);
    edge_mfma_kernel<64, 64><<<1024, 256, 0, stream>>>(xcat, 0, W2nh, W2nl, W2dh, W2dl, idxb, H1, P);
    bn_stats_kernel<<<64, 256, 0, stream>>>(P, 1024, 64, EC_CNT, g2, b2, abuf, cbuf);
    fin_fuse_rm_kernel<64><<<256, 256, 0, stream>>>(H1, abuf, cbuf, 64, xcat, xT, xxb);

    // ---- edge conv 3 (C=64 -> O=128) @ cols [128,256) ----
    knn_wl_kernel<64><<<2048, 256, 0, stream>>>(xT, xxb, idxb);
    edge_mfma_kernel<64, 128><<<1024, 256, 0, stream>>>(xcat, 64, W3nh, W3nl, W3dh, W3dl, idxb, H1, P);
    bn_stats_kernel<<<128, 256, 0, stream>>>(P, 1024, 128, EC_CNT, g3, b3, abuf, cbuf);
    fin_fuse_rm_kernel<128><<<256, 256, 0, stream>>>(H1, abuf, cbuf, 128, xcat, xT, xxb);

    // ---- edge conv 4 (C=128 -> O=256) @ cols [256,512) ----
    knn_wl_kernel<128><<<2048, 256, 0, stream>>>(xT, xxb, idxb);
    edge_mfma_kernel<128, 256><<<1024, 256, 0, stream>>>(xcat, 128, W4nh, W4nl, W4dh, W4dl, idxb, H1, P);
    bn_stats_kernel<<<256, 256, 0, stream>>>(P, 1024, 256, EC_CNT, g4, b4, abuf, cbuf);
    edge_fin_rm_kernel<<<B_ * N_ * 256 / 256, 256, 0, stream>>>(H1, abuf, cbuf, 256, 256, xcat);

    // ---- conv5 (512 -> 1024) global max: bf16 stats + argmax, exact fp32 re-eval ----
    conv5_mfma_kernel<<<256, 256, 0, stream>>>(xcat, W5b, part5, mpart5, mipart);
    bn_stats_kernel<<<1024, 256, 0, stream>>>(part5, 256, 1024, C1_CNT, g5, b5, abuf, cbuf);
    lf_kernel<<<1, 64, 0, stream>>>(l, W206, g206, b206, glob);
    finalize5_exact_kernel<<<2048, 256, 0, stream>>>(mpart5, mipart, xcat, W5, abuf, cbuf, glob);
    t207_kernel<<<8, 256, 0, stream>>>(W207, glob, tbuf);

    // ---- conv 207 (512 -> 256) ----
    conv_mfma_kernel<512, 256, true><<<256, 256, 0, stream>>>(xcat, W207h, W207l, tbuf, h207, P);
    bn_stats_kernel<<<256, 256, 0, stream>>>(P, 1024, 256, C1_CNT, g207, b207, abuf, cbuf);
    bn_act_rm_kernel<<<B_ * N_ * 256 / 256, 256, 0, stream>>>(h207, abuf, cbuf, 256);

    // ---- conv 208 (256 -> 256) ----
    conv_mfma_kernel<256, 256, false><<<256, 256, 0, stream>>>(h207, W208h, W208l, nullptr, h208, P);
    bn_stats_kernel<<<256, 256, 0, stream>>>(P, 1024, 256, C1_CNT, g208, b208, abuf, cbuf);
    bn_act_rm_kernel<<<B_ * N_ * 256 / 256, 256, 0, stream>>>(h208, abuf, cbuf, 256);

    // ---- conv 209 (256 -> 128) ----
    conv_mfma_kernel<256, 128, false><<<256, 256, 0, stream>>>(h208, W209h, W209l, nullptr, h209, P);
    bn_stats_kernel<<<128, 256, 0, stream>>>(P, 1024, 128, C1_CNT, g209, b209, abuf, cbuf);
    bn_act_rm_kernel<<<B_ * N_ * 128 / 256, 256, 0, stream>>>(h209, abuf, cbuf, 128);

    // ---- final (128 -> 50), fp32 out ----
    final_rm_kernel<<<(B_ * 50 * N_ + 255) / 256, 256, 0, stream>>>(h209, W2010, (float*)d_out);
}